// Round 7
// baseline (319.049 us; speedup 1.0000x reference)
//
#include <hip/hip_runtime.h>
#include <hip/hip_bf16.h>

#define D_MODEL 256
#define HEADS 4
#define HD 64
#define BATCH 4
#define SEQ 4096
#define NPOS (BATCH*SEQ)          // 16384 positions
#define SCALE_LOG2 0.18033688011112042f  // log2(e)/8, folded into q projection
#define MCHUNKS 2                 // flash m-split (partials add; no online max)

typedef __attribute__((ext_vector_type(4))) float floatx4;
typedef __attribute__((ext_vector_type(8))) short bf16x8;
typedef __attribute__((ext_vector_type(4))) short bf16x4;
typedef __attribute__((ext_vector_type(4))) unsigned short ushortx4;

__device__ __forceinline__ float bf2f(unsigned short b) {
    return __uint_as_float(((unsigned int)b) << 16);
}
__device__ __forceinline__ unsigned short f2bf(float f) {
    unsigned int u = __float_as_uint(f);
    return (unsigned short)((u + 0x7fffu + ((u >> 16) & 1u)) >> 16);
}
__device__ __forceinline__ bf16x4 pack_bf16x4(float a, float b, float c, float d) {
    __hip_bfloat162 lo = __float22bfloat162_rn(float2{a, b});
    __hip_bfloat162 hi = __float22bfloat162_rn(float2{c, d});
    union { __hip_bfloat162 h2[2]; bf16x4 v; } u;
    u.h2[0] = lo; u.h2[1] = hi;
    return u.v;
}
__device__ __forceinline__ bf16x8 pack_bf16x8(floatx4 a, floatx4 b) {
    union { bf16x4 h[2]; bf16x8 v; } u;
    u.h[0] = pack_bf16x4(a[0], a[1], a[2], a[3]);
    u.h[1] = pack_bf16x4(b[0], b[1], b[2], b[3]);
    return u.v;
}
#define MFMA(a,b,c) __builtin_amdgcn_mfma_f32_16x16x32_bf16((a),(b),(c),0,0,0)

// ---------------------------------------------------------------------------
// prep: blocks [0,576): linear f32->bf16 weight copies (pq,pk,pv,mlp1,mlp2).
//       blocks [576,640): Wmt[c'][o] = merge_w[o][(c'&63)*4 + (c'>>6)].
//       blocks [640,1152): transpose x/source -> xT/srcT [pos][256] bf16.
// ---------------------------------------------------------------------------
__global__ __launch_bounds__(256) void prep(
        const float* __restrict__ pq_w, const float* __restrict__ pk_w,
        const float* __restrict__ pv_w, const float* __restrict__ merge_w,
        const float* __restrict__ mlp1_w, const float* __restrict__ mlp2_w,
        const float* __restrict__ x, const float* __restrict__ src,
        unsigned short* __restrict__ wqb, unsigned short* __restrict__ wkb,
        unsigned short* __restrict__ wvb, unsigned short* __restrict__ wmt,
        unsigned short* __restrict__ w1b, unsigned short* __restrict__ w2b,
        unsigned short* __restrict__ xT, unsigned short* __restrict__ srcT)
{
    __shared__ unsigned short lT[64][264];
    const int t = threadIdx.x;
    const int bx = blockIdx.x;
    if (bx < 576) {
        int linear = bx * 1024 + t * 4;
        const float* srcW; unsigned short* dst; int off;
        if (linear < 65536)       { srcW = pq_w;   dst = wqb; off = 0; }
        else if (linear < 131072) { srcW = pk_w;   dst = wkb; off = 65536; }
        else if (linear < 196608) { srcW = pv_w;   dst = wvb; off = 131072; }
        else if (linear < 458752) { srcW = mlp1_w; dst = w1b; off = 196608; }
        else                      { srcW = mlp2_w; dst = w2b; off = 458752; }
        int i = linear - off;
        float4 w = *(const float4*)&srcW[i];
        ushortx4 s = { f2bf(w.x), f2bf(w.y), f2bf(w.z), f2bf(w.w) };
        *(ushortx4*)&dst[i] = s;
        return;
    }
    if (bx < 640) {
        int i = (bx - 576) * 1024 + t * 4;
        int cp = i >> 8, o = i & 255;
        int pc = ((cp & 63) << 2) | (cp >> 6);
        unsigned short s[4];
#pragma unroll
        for (int j = 0; j < 4; ++j)
            s[j] = f2bf(merge_w[(size_t)(o + j) * 256 + pc]);
        *(ushortx4*)&wmt[i] = *(const ushortx4*)s;
        return;
    }
    int z = bx - 640;
    const float* X = (z < 256) ? x : src;
    unsigned short* O = (z < 256) ? xT : srcT;
    int rem = z & 255;
    int b = rem >> 6, n0 = (rem & 63) * 64;
#pragma unroll
    for (int r = 0; r < 16; ++r) {
        int idx = r * 256 + t;
        int ch = idx >> 4, nnq = (idx & 15) * 4;
        float4 v4 = *(const float4*)&X[((size_t)b * 256 + ch) * SEQ + n0 + nnq];
        lT[nnq + 0][ch] = f2bf(v4.x);
        lT[nnq + 1][ch] = f2bf(v4.y);
        lT[nnq + 2][ch] = f2bf(v4.z);
        lT[nnq + 3][ch] = f2bf(v4.w);
    }
    __syncthreads();
#pragma unroll
    for (int r = 0; r < 8; ++r) {
        int idx = r * 256 + t;
        int row = idx >> 5, cg = (idx & 31) * 8;
        *(bf16x8*)&O[((size_t)b * SEQ + n0 + row) * 256 + cg] = *(const bf16x8*)&lT[row][cg];
    }
}

// ---------------------------------------------------------------------------
// prep2: fold merge into mlp1.  y<8: w1f[o2][c'] = sum_o W1b[o2][o]*Wmt[c'][o];
// y==8: b1f[o2] = mlp1_b[o2] + sum_o W1b[o2][o]*merge_b[o].  grid (2,9).
// ---------------------------------------------------------------------------
__global__ __launch_bounds__(256) void prep2(
        const float* __restrict__ mlp1_w, const float* __restrict__ mlp1_b,
        const float* __restrict__ merge_b, const unsigned short* __restrict__ wmt,
        unsigned short* __restrict__ w1f, float* __restrict__ b1f)
{
    __shared__ unsigned short lA[64][40];
    __shared__ unsigned short lB[128][40];
    const int t = threadIdx.x;
    if (blockIdx.y == 8) {
        int o2 = blockIdx.x * 256 + t;
        float s = mlp1_b[o2];
        for (int o = 0; o < 256; ++o)
            s += mlp1_w[(size_t)o2 * 512 + 256 + o] * merge_b[o];
        b1f[o2] = s;
        return;
    }
    const int lane = t & 63, wid = t >> 6;
    const int wm = wid >> 1, wn = wid & 1;
    const int lrow = lane & 15, quad = lane >> 4;
    const int o20 = blockIdx.y * 64;
    const int c0  = blockIdx.x * 128;

    floatx4 acc[2][4];
#pragma unroll
    for (int i = 0; i < 2; ++i)
#pragma unroll
        for (int j = 0; j < 4; ++j) acc[i][j] = (floatx4){0.f,0.f,0.f,0.f};

    for (int k0 = 0; k0 < 256; k0 += 32) {
#pragma unroll
        for (int r = 0; r < 2; ++r) {
            int linear = r * 1024 + t * 4;
            int row = linear >> 5, col = linear & 31;
            float4 w = *(const float4*)&mlp1_w[(size_t)(o20 + row) * 512 + 256 + k0 + col];
            ushortx4 s = { f2bf(w.x), f2bf(w.y), f2bf(w.z), f2bf(w.w) };
            *(ushortx4*)&lA[row][col] = s;
        }
#pragma unroll
        for (int r = 0; r < 2; ++r) {
            int linear = r * 256 + t;
            int row = linear >> 2, cg = (linear & 3) * 8;
            *(bf16x8*)&lB[row][cg] = *(const bf16x8*)&wmt[(size_t)(c0 + row) * 256 + k0 + cg];
        }
        __syncthreads();
        bf16x8 aF[2], bF[4];
        const int kq = quad * 8;
#pragma unroll
        for (int mt = 0; mt < 2; ++mt)
            aF[mt] = *(const bf16x8*)&lA[wm*32 + mt*16 + lrow][kq];
#pragma unroll
        for (int nt = 0; nt < 4; ++nt)
            bF[nt] = *(const bf16x8*)&lB[wn*64 + nt*16 + lrow][kq];
#pragma unroll
        for (int mt = 0; mt < 2; ++mt)
#pragma unroll
            for (int nt = 0; nt < 4; ++nt)
                acc[mt][nt] = MFMA(aF[mt], bF[nt], acc[mt][nt]);
        __syncthreads();
    }
#pragma unroll
    for (int nt = 0; nt < 4; ++nt) {
        int cp = c0 + wn*64 + nt*16 + lrow;
#pragma unroll
        for (int mt = 0; mt < 2; ++mt)
#pragma unroll
            for (int j = 0; j < 4; ++j) {
                int o2 = o20 + wm*32 + mt*16 + quad*4 + j;
                w1f[(size_t)o2 * 256 + cp] = f2bf(acc[mt][nt][j]);
            }
    }
}

// ---------------------------------------------------------------------------
// Merged QKV projection with register-prefetch pipeline.
// grid (6, SEQ/128, B): mode = x>>1 (0=q,1=k,2=v), ob = (x&1)*128.
// ---------------------------------------------------------------------------
__global__ __launch_bounds__(256) void proj_qkv_all(
        const unsigned short* __restrict__ Wq, const float* __restrict__ bq,
        const unsigned short* __restrict__ Wk, const float* __restrict__ bk,
        const unsigned short* __restrict__ Wv, const float* __restrict__ bv,
        const unsigned short* __restrict__ xT, const unsigned short* __restrict__ srcT,
        unsigned short* __restrict__ qo, unsigned short* __restrict__ ko,
        unsigned short* __restrict__ vo)
{
    __shared__ unsigned short smem[128 * 80];   // lA(128x40)+lB(128x40); reused as stage[128][72]
    unsigned short (*lA)[40] = (unsigned short (*)[40])smem;
    unsigned short (*lB)[40] = (unsigned short (*)[40])(smem + 128 * 40);
    unsigned short (*stage)[72] = (unsigned short (*)[72])smem;
    const int t = threadIdx.x;
    const int lane = t & 63, wid = t >> 6;
    const int wm = wid >> 1, wn = wid & 1;
    const int lrow = lane & 15, quad = lane >> 4;
    const int mode = blockIdx.x >> 1;
    const int ob = (blockIdx.x & 1) * 128;
    const int n0 = blockIdx.y * 128;
    const int b  = blockIdx.z;
    const unsigned short* W  = (mode == 0) ? Wq : (mode == 1) ? Wk : Wv;
    const float* bias        = (mode == 0) ? bq : (mode == 1) ? bk : bv;
    const unsigned short* XT = (mode == 0) ? xT : srcT;
    unsigned short* out      = (mode == 0) ? qo : (mode == 1) ? ko : vo;

    const int srow[2] = { (0*256 + t) >> 2, (1*256 + t) >> 2 };
    const int scg = (t & 3) * 8;

    floatx4 acc[4][4];
#pragma unroll
    for (int i = 0; i < 4; ++i)
#pragma unroll
        for (int j = 0; j < 4; ++j) acc[i][j] = (floatx4){0.f,0.f,0.f,0.f};

    bf16x8 rW[2], rX[2];
#pragma unroll
    for (int r = 0; r < 2; ++r) {              // prologue: tile 0 -> regs -> LDS
        rW[r] = *(const bf16x8*)&W[(size_t)(ob + srow[r]) * 256 + scg];
        rX[r] = *(const bf16x8*)&XT[((size_t)b * SEQ + n0 + srow[r]) * 256 + scg];
    }
#pragma unroll
    for (int r = 0; r < 2; ++r) {
        *(bf16x8*)&lA[srow[r]][scg] = rW[r];
        *(bf16x8*)&lB[srow[r]][scg] = rX[r];
    }
    __syncthreads();

    for (int kc = 0; kc < 8; ++kc) {
        const bool pre = (kc + 1 < 8);
        if (pre) {
            const int k1 = (kc + 1) * 32;
#pragma unroll
            for (int r = 0; r < 2; ++r) {
                rW[r] = *(const bf16x8*)&W[(size_t)(ob + srow[r]) * 256 + k1 + scg];
                rX[r] = *(const bf16x8*)&XT[((size_t)b * SEQ + n0 + srow[r]) * 256 + k1 + scg];
            }
        }
        bf16x8 aF[4], bF[4];
        const int kq = quad * 8;
#pragma unroll
        for (int mt = 0; mt < 4; ++mt)
            aF[mt] = *(const bf16x8*)&lA[wm*64 + mt*16 + lrow][kq];
#pragma unroll
        for (int nt = 0; nt < 4; ++nt)
            bF[nt] = *(const bf16x8*)&lB[wn*64 + nt*16 + lrow][kq];
#pragma unroll
        for (int mt = 0; mt < 4; ++mt)
#pragma unroll
            for (int nt = 0; nt < 4; ++nt)
                acc[mt][nt] = MFMA(aF[mt], bF[nt], acc[mt][nt]);
        __syncthreads();
        if (pre) {
#pragma unroll
            for (int r = 0; r < 2; ++r) {
                *(bf16x8*)&lA[srow[r]][scg] = rW[r];
                *(bf16x8*)&lB[srow[r]][scg] = rX[r];
            }
            __syncthreads();
        }
    }
    const float osc = (mode == 0) ? SCALE_LOG2 : 1.0f;
    if (mode == 2) {
        // v: direct epilogue, [bh][d][m]: 32B contiguous per quad-group
#pragma unroll
        for (int mt = 0; mt < 4; ++mt) {
#pragma unroll
            for (int j = 0; j < 4; ++j) {
                int o = ob + wm*64 + mt*16 + quad*4 + j;
                float bvv = bias[o];
                int d = o >> 2, h = o & 3;
#pragma unroll
                for (int nt = 0; nt < 4; ++nt) {
                    int n = n0 + wn*64 + nt*16 + lrow;
                    out[((size_t)(b*HEADS + h) * HD + d) * SEQ + n] = f2bf(acc[mt][nt][j] + bvv);
                }
            }
        }
        return;
    }
    // q/k: LDS-staged epilogue -> [bh][n][64]
    for (int half = 0; half < 2; ++half) {
        __syncthreads();
        if (wm == half) {
#pragma unroll
            for (int mt = 0; mt < 4; ++mt)
#pragma unroll
                for (int j = 0; j < 4; ++j) {
                    int o = ob + half*64 + mt*16 + quad*4 + j;
                    float bvv = bias[o];
                    int col = j*16 + mt*4 + quad;
#pragma unroll
                    for (int nt = 0; nt < 4; ++nt) {
                        int n = wn*64 + nt*16 + lrow;
                        stage[n][col] = f2bf((acc[mt][nt][j] + bvv) * osc);
                    }
                }
        }
        __syncthreads();
#pragma unroll
        for (int i = 0; i < 4; ++i) {
            int c = i * 256 + t;
            int n = c >> 3, h = (c >> 1) & 3, sub = c & 1;
            bf16x8 val = *(const bf16x8*)&stage[n][h*16 + sub*8];
            int d0 = (ob >> 2) + half*16 + sub*8;
            *(bf16x8*)&out[((size_t)(b*HEADS + h) * SEQ + n0 + n) * HD + d0] = val;
        }
    }
}

// ---------------------------------------------------------------------------
// Flash attention, transposed-softmax, m-split, double-buffered LDS.
// grid (32, SEQ/128): blockIdx.x = chunk*16+bh (XCD swizzle), blockIdx.y = qt.
// Denominator l via all-ones-A MFMA.  Partial O bf16, plain stores (L2
// write-combining; nt amplified writes 7x — R6 post-mortem).
// ---------------------------------------------------------------------------
__global__ __launch_bounds__(256, 4) void flash_attn(
        const unsigned short* __restrict__ q,
        const unsigned short* __restrict__ k,
        const unsigned short* __restrict__ v,
        unsigned short* __restrict__ poO, float* __restrict__ pol)
{
    __shared__ unsigned short smem[2][9216];   // per buf: lK 64x72 then lV 64x72
    const int t = threadIdx.x, lane = t & 63, wid = t >> 6;
    const int lrow = lane & 15, quad = lane >> 4;
    const int bc = blockIdx.x, qt = blockIdx.y;
    const int bh = bc & 15, chunk = bc >> 4;
    const int hb = (bh & 3) * BATCH + (bh >> 2);   // h*BATCH+b for attn' order
    const int r0 = qt * 128 + wid * 32;

    bf16x8 qf[2][2];
#pragma unroll
    for (int nh = 0; nh < 2; ++nh) {
        const size_t base = ((size_t)bh * SEQ + r0 + nh*16 + lrow) * HD;
        qf[nh][0] = *(const bf16x8*)&q[base + quad * 8];
        qf[nh][1] = *(const bf16x8*)&q[base + 32 + quad * 8];
    }
    bf16x8 ones;
#pragma unroll
    for (int i = 0; i < 8; ++i) ones[i] = (short)0x3F80;  // bf16 1.0
    int mmv[2], cgv[2], krv[2];
#pragma unroll
    for (int r = 0; r < 2; ++r) {
        int linear = r * 256 + t;
        int mm = linear >> 3, cg = (linear & 7) * 8;
        int c2 = mm >> 5, mp = mm & 31;
        mmv[r] = mm; cgv[r] = cg;
        krv[r] = (c2 << 5) + ((mp & 4) << 2) + ((mp >> 3) << 2) + (mp & 3);
    }
    const size_t kbase = ((size_t)bh * SEQ + chunk * (SEQ/MCHUNKS));
    const size_t vbase = (size_t)bh * HD;
    const int moff = chunk * (SEQ/MCHUNKS);
    const int NIT = SEQ / MCHUNKS / 64;

    floatx4 oacc[2][4], oaccL[2];
#pragma unroll
    for (int nh = 0; nh < 2; ++nh) {
        oaccL[nh] = (floatx4){0.f,0.f,0.f,0.f};
#pragma unroll
        for (int i = 0; i < 4; ++i) oacc[nh][i] = (floatx4){0.f,0.f,0.f,0.f};
    }

    {
        bf16x8 pk[2], pv[2];
#pragma unroll
        for (int r = 0; r < 2; ++r) {
            pk[r] = *(const bf16x8*)&k[(kbase + mmv[r]) * HD + cgv[r]];
            pv[r] = *(const bf16x8*)&v[(vbase + mmv[r]) * SEQ + moff + cgv[r]];
        }
#pragma unroll
        for (int r = 0; r < 2; ++r) {
            *(bf16x8*)&smem[0][krv[r]*72 + cgv[r]]        = pk[r];
            *(bf16x8*)&smem[0][4608 + mmv[r]*72 + cgv[r]] = pv[r];
        }
    }
    __syncthreads();

    int p = 0;
#pragma unroll 1
    for (int it = 0; it < NIT; ++it) {
        bf16x8 pk[2], pv[2];
        const bool pre = (it + 1 < NIT);
        if (pre) {
            const int m1 = (it + 1) * 64;
#pragma unroll
            for (int r = 0; r < 2; ++r) {
                pk[r] = *(const bf16x8*)&k[(kbase + m1 + mmv[r]) * HD + cgv[r]];
                pv[r] = *(const bf16x8*)&v[(vbase + mmv[r]) * SEQ + moff + m1 + cgv[r]];
            }
        }
        const unsigned short* lK = smem[p];
        const unsigned short* lV = smem[p] + 4608;

        bf16x8 pf8[2][2];
#pragma unroll
        for (int c2 = 0; c2 < 2; ++c2) {
            floatx4 sa[2][2];
#pragma unroll
            for (int AB = 0; AB < 2; ++AB) {
                sa[AB][0] = (floatx4){0.f,0.f,0.f,0.f};
                sa[AB][1] = (floatx4){0.f,0.f,0.f,0.f};
#pragma unroll
                for (int kc = 0; kc < 2; ++kc) {
                    bf16x8 kf = *(const bf16x8*)&lK[(c2*32 + AB*16 + lrow)*72 + kc*32 + quad*8];
                    sa[AB][0] = MFMA(kf, qf[0][kc], sa[AB][0]);
                    sa[AB][1] = MFMA(kf, qf[1][kc], sa[AB][1]);
                }
            }
#pragma unroll
            for (int nh = 0; nh < 2; ++nh) {
                floatx4 ea, eb;
#pragma unroll
                for (int i = 0; i < 4; ++i) { ea[i] = exp2f(sa[0][nh][i]); eb[i] = exp2f(sa[1][nh][i]); }
                pf8[c2][nh] = pack_bf16x8(ea, eb);
            }
        }
#pragma unroll
        for (int c2 = 0; c2 < 2; ++c2) {
            oaccL[0] = MFMA(ones, pf8[c2][0], oaccL[0]);
            oaccL[1] = MFMA(ones, pf8[c2][1], oaccL[1]);
#pragma unroll
            for (int dt = 0; dt < 4; ++dt) {
                bf16x8 vf = *(const bf16x8*)&lV[(dt*16 + lrow)*72 + c2*32 + quad*8];
                oacc[0][dt] = MFMA(vf, pf8[c2][0], oacc[0][dt]);
                oacc[1][dt] = MFMA(vf, pf8[c2][1], oacc[1][dt]);
            }
        }
        if (pre) {
#pragma unroll
            for (int r = 0; r < 2; ++r) {
                *(bf16x8*)&smem[p^1][krv[r]*72 + cgv[r]]        = pk[r];
                *(bf16x8*)&smem[p^1][4608 + mmv[r]*72 + cgv[r]] = pv[r];
            }
        }
        __syncthreads();
        p ^= 1;
    }
    const size_t prow = (size_t)(chunk*16 + hb) * SEQ + qt * 128;
    if (lane < 16) {
        pol[prow + wid*32 + lrow]      = oaccL[0][0];
        pol[prow + wid*32 + 16 + lrow] = oaccL[1][0];
    }
    unsigned short* stB = (unsigned short*)&smem[0][0];   // [128][72] bf16
#pragma unroll
    for (int nh = 0; nh < 2; ++nh)
#pragma unroll
        for (int dt = 0; dt < 4; ++dt)
#pragma unroll
            for (int j = 0; j < 4; ++j)
                stB[(wid*32 + nh*16 + lrow)*72 + dt*16 + quad*4 + j] = f2bf(oacc[nh][dt][j]);
    __syncthreads();
#pragma unroll
    for (int i = 0; i < 4; ++i) {
        int c = i * 256 + t;
        int row = c >> 3, sub = c & 7;
        *(bf16x8*)&poO[(prow + row) * HD + sub*8] = *(const bf16x8*)&stB[row*72 + sub*8];
    }
}

// ---------------------------------------------------------------------------
// mlp1 (merge folded, LDS double-buffered, 1 barrier/iter):
// h1[pos][512] = xT@w1b[:,0:256]^T + attnC'@w1f^T + b1f;  attnC' combined
// on the fly from bf16 poO partials + pol.  Fused BN stats atomics.
// grid (4, NPOS/64), block 256.
// ---------------------------------------------------------------------------
__global__ __launch_bounds__(256) void gemm_mlp1(
        const unsigned short* __restrict__ xT, const unsigned short* __restrict__ poO,
        const float* __restrict__ pol,
        const unsigned short* __restrict__ w1b, const unsigned short* __restrict__ w1f,
        const float* __restrict__ b1f, unsigned short* __restrict__ h1,
        float* __restrict__ sums, float* __restrict__ sumsq)
{
    __shared__ unsigned short lA[2][64][40];
    __shared__ unsigned short lB[2][128][40];
    __shared__ float sInv[256];             // [h*64+n] inverse denominators
    const int t = threadIdx.x;
    const int lane = t & 63, wid = t >> 6;
    const int wm = wid >> 1, wn = wid & 1;
    const int lrow = lane & 15, quad = lane >> 4;
    const int o0 = blockIdx.x * 128;
    const int p0 = blockIdx.y * 64;
    const int b = p0 >> 12, n0 = p0 & (SEQ - 1);
    const size_t CH = (size_t)16 * SEQ * HD;

    {
        int h = t >> 6, nn = t & 63;
        int hb = h * BATCH + b;
        float l0 = pol[(size_t)hb * SEQ + n0 + nn];
        float l1 = pol[(size_t)(16 + hb) * SEQ + n0 + nn];
        sInv[t] = 1.0f / (l0 + l1);
    }
    __syncthreads();                         // sInv ready (also covers LDS reuse)

    const int arow = t >> 2, acg = (t & 3) * 8;
    const int brow[2] = { (0*256 + t) >> 2, (1*256 + t) >> 2 };

    floatx4 acc[2][4];
#pragma unroll
    for (int i = 0; i < 2; ++i)
#pragma unroll
        for (int j = 0; j < 4; ++j) acc[i][j] = (floatx4){0.f,0.f,0.f,0.f};

    bf16x8 rA, rB[2];
    auto load_tile = [&](int k0) {
        if (k0 < 256) {
            rA = *(const bf16x8*)&xT[(size_t)(p0 + arow) * 256 + k0 + acg];
#pragma unroll
            for (int r = 0; r < 2; ++r)
                rB[r] = *(const bf16x8*)&w1b[(size_t)(o0 + brow[r]) * 512 + k0 + acg];
        } else {
            const int kk2 = k0 - 256;
            const int h = kk2 >> 6, d0 = kk2 & 63, hb = h * BATCH + b;
            const unsigned short* bse = &poO[((size_t)hb * SEQ + n0 + arow) * HD + d0 + acg];
            bf16x8 a0 = *(const bf16x8*)bse;
            bf16x8 a1 = *(const bf16x8*)(bse + CH);
            float inv = sInv[h*64 + arow];
            unsigned short res[8];
#pragma unroll
            for (int i = 0; i < 8; ++i)
                res[i] = f2bf((bf2f((unsigned short)a0[i]) + bf2f((unsigned short)a1[i])) * inv);
            rA = *(const bf16x8*)res;
#pragma unroll
            for (int r = 0; r < 2; ++r)
                rB[r] = *(const bf16x8*)&w1f[(size_t)(o0 + brow[r]) * 256 + kk2 + acg];
        }
    };

    load_tile(0);
    *(bf16x8*)&lA[0][arow][acg] = rA;
#pragma unroll
    for (int r = 0; r < 2; ++r) *(bf16x8*)&lB[0][brow[r]][acg] = rB[r];
    __syncthreads();

    int p = 0;
    for (int kc = 0; kc < 16; ++kc) {
        const bool pre = (kc + 1 < 16);
        if (pre) load_tile((kc + 1) * 32);
        bf16x8 aF[2], bF[4];
        const int kq = quad * 8;
#pragma unroll
        for (int mt = 0; mt < 2; ++mt)
            aF[mt] = *(const bf16x8*)&lA[p][wm*32 + mt*16 + lrow][kq];
#pragma unroll
        for (int nt = 0; nt < 4; ++nt)
            bF[nt] = *(const bf16x8*)&lB[p][wn*64 + nt*16 + lrow][kq];
#pragma unroll
        for (int mt = 0; mt < 2; ++mt)
#pragma unroll
            for (int nt = 0; nt < 4; ++nt)
                acc[mt][nt] = MFMA(aF[mt], bF[nt], acc[mt][nt]);
        if (pre) {
            *(bf16x8*)&lA[p^1][arow][acg] = rA;
#pragma unroll
            for (int r = 0; r < 2; ++r) *(bf16x8*)&lB[p^1][brow[r]][acg] = rB[r];
        }
        __syncthreads();
        p ^= 1;
    }
#pragma unroll
    for (int nt = 0; nt < 4; ++nt) {
        int o = o0 + wn*64 + nt*16 + lrow;
        float bvv = b1f[o];
        float s = 0.f, qs = 0.f;
#pragma unroll
        for (int mt = 0; mt < 2; ++mt)
#pragma unroll
            for (int j = 0; j < 4; ++j) {
                int pos = p0 + wm*32 + mt*16 + quad*4 + j;
                float val = acc[mt][nt][j] + bvv;
                h1[(size_t)pos * 512 + o] = f2bf(val);
                s += val; qs += val * val;
            }
        s  += __shfl_xor(s, 16);  s  += __shfl_xor(s, 32);
        qs += __shfl_xor(qs, 16); qs += __shfl_xor(qs, 32);
        if (lane < 16) {
            atomicAdd(&sums[o], s);
            atomicAdd(&sumsq[o], qs);
        }
    }
}

// ---------------------------------------------------------------------------
// mlp2 (bf16 W, inline bn_final, LDS double-buffered, 1 barrier/iter):
// out[b][o][n] f32 = W2 @ relu(bn(h1))^T + bias. grid (2, NPOS/64).
// ---------------------------------------------------------------------------
__global__ __launch_bounds__(256) void gemm_mlp2(
        const unsigned short* __restrict__ W2, const unsigned short* __restrict__ h1,
        const float* __restrict__ bias,
        const float* __restrict__ sums, const float* __restrict__ sumsq,
        const float* __restrict__ gamma, const float* __restrict__ beta,
        float* __restrict__ out)
{
    __shared__ unsigned short lA[2][128][40];  // W [o][k]
    __shared__ unsigned short lB[2][64][40];   // act [pos][k]
    __shared__ float sSc[512], sSh[512];
    const int t = threadIdx.x;
    const int lane = t & 63, wid = t >> 6;
    const int wm = wid >> 1, wn = wid & 1;
    const int lrow = lane & 15, quad = lane >> 4;
    const int o0 = blockIdx.x * 128;
    const int p0 = blockIdx.y * 64;

#pragma unroll
    for (int cc = 0; cc < 2; ++cc) {        // inline bn_final (redundant per block)
        int c = cc * 256 + t;
        float mean = sums[c] * (1.0f / NPOS);
        float var  = sumsq[c] * (1.0f / NPOS) - mean * mean;
        float sc = gamma[c] * rsqrtf(var + 1e-5f);
        sSc[c] = sc;
        sSh[c] = beta[c] - mean * sc;
    }
    __syncthreads();

    const int arow[2] = { (0*256 + t) >> 2, (1*256 + t) >> 2 };
    const int acg = (t & 3) * 8;
    const int brow = t >> 2;

    floatx4 acc[4][2];
#pragma unroll
    for (int i = 0; i < 4; ++i)
#pragma unroll
        for (int j = 0; j < 2; ++j) acc[i][j] = (floatx4){0.f,0.f,0.f,0.f};

    bf16x8 rW[2], rH;
    auto load_tile = [&](int k0) {
#pragma unroll
        for (int r = 0; r < 2; ++r)
            rW[r] = *(const bf16x8*)&W2[(size_t)(o0 + arow[r]) * 512 + k0 + acg];
        bf16x8 hv = *(const bf16x8*)&h1[(size_t)(p0 + brow) * 512 + k0 + acg];
        unsigned short res[8];
#pragma unroll
        for (int i = 0; i < 8; ++i) {
            int c = k0 + acg + i;
            float f = bf2f((unsigned short)hv[i]);
            f = fmaxf(f * sSc[c] + sSh[c], 0.f);
            res[i] = f2bf(f);
        }
        rH = *(const bf16x8*)res;
    };

    load_tile(0);
#pragma unroll
    for (int r = 0; r < 2; ++r) *(bf16x8*)&lA[0][arow[r]][acg] = rW[r];
    *(bf16x8*)&lB[0][brow][acg] = rH;
    __syncthreads();

    int p = 0;
    for (int kc = 0; kc < 16; ++kc) {
        const bool pre = (kc + 1 < 16);
        if (pre) load_tile((kc + 1) * 32);
        bf16x8 aF[4], bF[2];
        const int kq = quad * 8;
#pragma unroll
        for (int mt = 0; mt < 4; ++mt)
            aF[mt] = *(const bf16x8*)&lA[p][wm*64 + mt*16 + lrow][kq];
#pragma unroll
        for (int nt = 0; nt < 2; ++nt)
            bF[nt] = *(const bf16x8*)&lB[p][wn*32 + nt*16 + lrow][kq];
#pragma unroll
        for (int mt = 0; mt < 4; ++mt)
#pragma unroll
            for (int nt = 0; nt < 2; ++nt)
                acc[mt][nt] = MFMA(aF[mt], bF[nt], acc[mt][nt]);
        if (pre) {
#pragma unroll
            for (int r = 0; r < 2; ++r) *(bf16x8*)&lA[p^1][arow[r]][acg] = rW[r];
            *(bf16x8*)&lB[p^1][brow][acg] = rH;
        }
        __syncthreads();
        p ^= 1;
    }
#pragma unroll
    for (int mt = 0; mt < 4; ++mt)
#pragma unroll
        for (int j = 0; j < 4; ++j) {
            int o = o0 + wm*64 + mt*16 + quad*4 + j;
            float bvv = bias[o];
#pragma unroll
            for (int nt = 0; nt < 2; ++nt) {
                int pos = p0 + wn*32 + nt*16 + lrow;
                int b = pos >> 12, n = pos & (SEQ - 1);
                out[((size_t)b * D_MODEL + o) * SEQ + n] = acc[mt][nt][j] + bvv;
            }
        }
}

// ---------------------------------------------------------------------------
extern "C" void kernel_launch(void* const* d_in, const int* in_sizes, int n_in,
                              void* d_out, int out_size, void* d_ws, size_t ws_size,
                              hipStream_t stream)
{
    (void)in_sizes; (void)n_in; (void)out_size; (void)ws_size;
    const float* x        = (const float*)d_in[0];
    const float* source   = (const float*)d_in[1];
    const float* pq_w     = (const float*)d_in[2];
    const float* pq_b     = (const float*)d_in[3];
    const float* pk_w     = (const float*)d_in[4];
    const float* pk_b     = (const float*)d_in[5];
    const float* pv_w     = (const float*)d_in[6];
    const float* pv_b     = (const float*)d_in[7];
    const float* merge_w  = (const float*)d_in[8];
    const float* merge_b  = (const float*)d_in[9];
    const float* mlp1_w   = (const float*)d_in[10];
    const float* mlp1_b   = (const float*)d_in[11];
    const float* bn_gamma = (const float*)d_in[12];
    const float* bn_beta  = (const float*)d_in[13];
    const float* mlp2_w   = (const float*)d_in[14];
    const float* mlp2_b   = (const float*)d_in[15];
    float* out = (float*)d_out;

    char* ws = (char*)d_ws;
    const size_t MB = 1ull << 20;
    unsigned short* xT   = (unsigned short*)(ws);             //  8 MB [pos][256]
    unsigned short* srcT = (unsigned short*)(ws + 8*MB);      //  8 MB [pos][256]
    unsigned short* q    = (unsigned short*)(ws + 16*MB);     //  8 MB [bh][n][64]
    unsigned short* kk   = (unsigned short*)(ws + 24*MB);     //  8 MB [bh][m][64]
    unsigned short* v    = (unsigned short*)(ws + 32*MB);     //  8 MB [bh][64][m]
    unsigned short* poO  = (unsigned short*)(ws + 40*MB);     // 16 MB bf16 partial O
    unsigned short* h1   = (unsigned short*)(ws + 57*MB);     // 16 MB [pos][512]
    float* pol = (float*)(ws + 73*MB);                        // 512 KB partial l
    unsigned short* wqb = (unsigned short*)(ws + 74*MB);
    unsigned short* wkb = wqb + 65536;
    unsigned short* wvb = wkb + 65536;
    unsigned short* wmt = wvb + 65536;                        // [c'][o] 128 KB
    unsigned short* w1b = wmt + 65536;                        // 512 KB full mlp1_w
    unsigned short* w2b = w1b + 262144;                       // 256 KB
    unsigned short* w1f = w2b + 131072;                       // 256 KB folded
    float* b1f = (float*)(w1f + 131072);                      // 512 folded bias
    float* bn_sum = b1f + 512;
    float* bn_sumsq = bn_sum + 512;

    hipMemsetAsync(bn_sum, 0, 1024 * sizeof(float), stream);

    prep<<<dim3(1152), 256, 0, stream>>>(
        pq_w, pk_w, pv_w, merge_w, mlp1_w, mlp2_w, x, source,
        wqb, wkb, wvb, wmt, w1b, w2b, xT, srcT);
    prep2<<<dim3(2, 9), 256, 0, stream>>>(mlp1_w, mlp1_b, merge_b, wmt, w1f, b1f);
    proj_qkv_all<<<dim3(6, SEQ/128, BATCH), 256, 0, stream>>>(
        wqb, pq_b, wkb, pk_b, wvb, pv_b, xT, srcT, q, kk, v);
    flash_attn<<<dim3(16*MCHUNKS, SEQ/128), 256, 0, stream>>>(q, kk, v, poO, pol);
    gemm_mlp1<<<dim3(4, NPOS/64), 256, 0, stream>>>(
        xT, poO, pol, w1b, w1f, b1f, h1, bn_sum, bn_sumsq);
    gemm_mlp2<<<dim3(2, NPOS/64), 256, 0, stream>>>(
        w2b, h1, mlp2_b, bn_sum, bn_sumsq, bn_gamma, bn_beta, out);
}

// Round 8
// 277.936 us; speedup vs baseline: 1.1479x; 1.1479x over previous
//
#include <hip/hip_runtime.h>
#include <hip/hip_bf16.h>

#define D_MODEL 256
#define HEADS 4
#define HD 64
#define BATCH 4
#define SEQ 4096
#define NPOS (BATCH*SEQ)          // 16384 positions
#define SCALE_LOG2 0.18033688011112042f  // log2(e)/8, folded into q projection
#define MCHUNKS 2                 // flash m-split (partials add; no online max)

typedef __attribute__((ext_vector_type(4))) float floatx4;
typedef __attribute__((ext_vector_type(8))) short bf16x8;
typedef __attribute__((ext_vector_type(4))) short bf16x4;
typedef __attribute__((ext_vector_type(4))) unsigned short ushortx4;

__device__ __forceinline__ float bf2f(unsigned short b) {
    return __uint_as_float(((unsigned int)b) << 16);
}
__device__ __forceinline__ unsigned short f2bf(float f) {
    unsigned int u = __float_as_uint(f);
    return (unsigned short)((u + 0x7fffu + ((u >> 16) & 1u)) >> 16);
}
__device__ __forceinline__ bf16x4 pack_bf16x4(float a, float b, float c, float d) {
    __hip_bfloat162 lo = __float22bfloat162_rn(float2{a, b});
    __hip_bfloat162 hi = __float22bfloat162_rn(float2{c, d});
    union { __hip_bfloat162 h2[2]; bf16x4 v; } u;
    u.h2[0] = lo; u.h2[1] = hi;
    return u.v;
}
__device__ __forceinline__ bf16x8 pack_bf16x8(floatx4 a, floatx4 b) {
    union { bf16x4 h[2]; bf16x8 v; } u;
    u.h[0] = pack_bf16x4(a[0], a[1], a[2], a[3]);
    u.h[1] = pack_bf16x4(b[0], b[1], b[2], b[3]);
    return u.v;
}
#define MFMA(a,b,c) __builtin_amdgcn_mfma_f32_16x16x32_bf16((a),(b),(c),0,0,0)
#define EXP2(x) __builtin_amdgcn_exp2f(x)   // native v_exp_f32 (exp2f -> ocml is ~5x slower)

// ---------------------------------------------------------------------------
// prep: blocks [0,576): linear f32->bf16 weight copies (pq,pk,pv,mlp1,mlp2).
//       blocks [576,640): Wmt[c'][o] = merge_w[o][(c'&63)*4 + (c'>>6)].
//       blocks [640,1152): transpose x/source -> xT/srcT [pos][256] bf16.
// ---------------------------------------------------------------------------
__global__ __launch_bounds__(256) void prep(
        const float* __restrict__ pq_w, const float* __restrict__ pk_w,
        const float* __restrict__ pv_w, const float* __restrict__ merge_w,
        const float* __restrict__ mlp1_w, const float* __restrict__ mlp2_w,
        const float* __restrict__ x, const float* __restrict__ src,
        unsigned short* __restrict__ wqb, unsigned short* __restrict__ wkb,
        unsigned short* __restrict__ wvb, unsigned short* __restrict__ wmt,
        unsigned short* __restrict__ w1b, unsigned short* __restrict__ w2b,
        unsigned short* __restrict__ xT, unsigned short* __restrict__ srcT)
{
    __shared__ unsigned short lT[64][264];
    const int t = threadIdx.x;
    const int bx = blockIdx.x;
    if (bx < 576) {
        int linear = bx * 1024 + t * 4;
        const float* srcW; unsigned short* dst; int off;
        if (linear < 65536)       { srcW = pq_w;   dst = wqb; off = 0; }
        else if (linear < 131072) { srcW = pk_w;   dst = wkb; off = 65536; }
        else if (linear < 196608) { srcW = pv_w;   dst = wvb; off = 131072; }
        else if (linear < 458752) { srcW = mlp1_w; dst = w1b; off = 196608; }
        else                      { srcW = mlp2_w; dst = w2b; off = 458752; }
        int i = linear - off;
        float4 w = *(const float4*)&srcW[i];
        ushortx4 s = { f2bf(w.x), f2bf(w.y), f2bf(w.z), f2bf(w.w) };
        *(ushortx4*)&dst[i] = s;
        return;
    }
    if (bx < 640) {
        int i = (bx - 576) * 1024 + t * 4;
        int cp = i >> 8, o = i & 255;
        int pc = ((cp & 63) << 2) | (cp >> 6);
        unsigned short s[4];
#pragma unroll
        for (int j = 0; j < 4; ++j)
            s[j] = f2bf(merge_w[(size_t)(o + j) * 256 + pc]);
        *(ushortx4*)&wmt[i] = *(const ushortx4*)s;
        return;
    }
    int z = bx - 640;
    const float* X = (z < 256) ? x : src;
    unsigned short* O = (z < 256) ? xT : srcT;
    int rem = z & 255;
    int b = rem >> 6, n0 = (rem & 63) * 64;
#pragma unroll
    for (int r = 0; r < 16; ++r) {
        int idx = r * 256 + t;
        int ch = idx >> 4, nnq = (idx & 15) * 4;
        float4 v4 = *(const float4*)&X[((size_t)b * 256 + ch) * SEQ + n0 + nnq];
        lT[nnq + 0][ch] = f2bf(v4.x);
        lT[nnq + 1][ch] = f2bf(v4.y);
        lT[nnq + 2][ch] = f2bf(v4.z);
        lT[nnq + 3][ch] = f2bf(v4.w);
    }
    __syncthreads();
#pragma unroll
    for (int r = 0; r < 8; ++r) {
        int idx = r * 256 + t;
        int row = idx >> 5, cg = (idx & 31) * 8;
        *(bf16x8*)&O[((size_t)b * SEQ + n0 + row) * 256 + cg] = *(const bf16x8*)&lT[row][cg];
    }
}

// ---------------------------------------------------------------------------
// prep2: fold merge into mlp1.  y<8: w1f[o2][c'] = sum_o W1b[o2][o]*Wmt[c'][o];
// y==8: b1f[o2] = mlp1_b[o2] + sum_o W1b[o2][o]*merge_b[o].  grid (2,9).
// ---------------------------------------------------------------------------
__global__ __launch_bounds__(256) void prep2(
        const float* __restrict__ mlp1_w, const float* __restrict__ mlp1_b,
        const float* __restrict__ merge_b, const unsigned short* __restrict__ wmt,
        unsigned short* __restrict__ w1f, float* __restrict__ b1f)
{
    __shared__ unsigned short lA[64][40];
    __shared__ unsigned short lB[128][40];
    const int t = threadIdx.x;
    if (blockIdx.y == 8) {
        int o2 = blockIdx.x * 256 + t;
        float s = mlp1_b[o2];
        for (int o = 0; o < 256; ++o)
            s += mlp1_w[(size_t)o2 * 512 + 256 + o] * merge_b[o];
        b1f[o2] = s;
        return;
    }
    const int lane = t & 63, wid = t >> 6;
    const int wm = wid >> 1, wn = wid & 1;
    const int lrow = lane & 15, quad = lane >> 4;
    const int o20 = blockIdx.y * 64;
    const int c0  = blockIdx.x * 128;

    floatx4 acc[2][4];
#pragma unroll
    for (int i = 0; i < 2; ++i)
#pragma unroll
        for (int j = 0; j < 4; ++j) acc[i][j] = (floatx4){0.f,0.f,0.f,0.f};

    for (int k0 = 0; k0 < 256; k0 += 32) {
#pragma unroll
        for (int r = 0; r < 2; ++r) {
            int linear = r * 1024 + t * 4;
            int row = linear >> 5, col = linear & 31;
            float4 w = *(const float4*)&mlp1_w[(size_t)(o20 + row) * 512 + 256 + k0 + col];
            ushortx4 s = { f2bf(w.x), f2bf(w.y), f2bf(w.z), f2bf(w.w) };
            *(ushortx4*)&lA[row][col] = s;
        }
#pragma unroll
        for (int r = 0; r < 2; ++r) {
            int linear = r * 256 + t;
            int row = linear >> 2, cg = (linear & 3) * 8;
            *(bf16x8*)&lB[row][cg] = *(const bf16x8*)&wmt[(size_t)(c0 + row) * 256 + k0 + cg];
        }
        __syncthreads();
        bf16x8 aF[2], bF[4];
        const int kq = quad * 8;
#pragma unroll
        for (int mt = 0; mt < 2; ++mt)
            aF[mt] = *(const bf16x8*)&lA[wm*32 + mt*16 + lrow][kq];
#pragma unroll
        for (int nt = 0; nt < 4; ++nt)
            bF[nt] = *(const bf16x8*)&lB[wn*64 + nt*16 + lrow][kq];
#pragma unroll
        for (int mt = 0; mt < 2; ++mt)
#pragma unroll
            for (int nt = 0; nt < 4; ++nt)
                acc[mt][nt] = MFMA(aF[mt], bF[nt], acc[mt][nt]);
        __syncthreads();
    }
#pragma unroll
    for (int nt = 0; nt < 4; ++nt) {
        int cp = c0 + wn*64 + nt*16 + lrow;
#pragma unroll
        for (int mt = 0; mt < 2; ++mt)
#pragma unroll
            for (int j = 0; j < 4; ++j) {
                int o2 = o20 + wm*32 + mt*16 + quad*4 + j;
                w1f[(size_t)o2 * 256 + cp] = f2bf(acc[mt][nt][j]);
            }
    }
}

// ---------------------------------------------------------------------------
// Merged QKV projection with register-prefetch pipeline.
// grid (6, SEQ/128, B): mode = x>>1 (0=q,1=k,2=v), ob = (x&1)*128.
// ---------------------------------------------------------------------------
__global__ __launch_bounds__(256) void proj_qkv_all(
        const unsigned short* __restrict__ Wq, const float* __restrict__ bq,
        const unsigned short* __restrict__ Wk, const float* __restrict__ bk,
        const unsigned short* __restrict__ Wv, const float* __restrict__ bv,
        const unsigned short* __restrict__ xT, const unsigned short* __restrict__ srcT,
        unsigned short* __restrict__ qo, unsigned short* __restrict__ ko,
        unsigned short* __restrict__ vo)
{
    __shared__ unsigned short smem[128 * 80];
    unsigned short (*lA)[40] = (unsigned short (*)[40])smem;
    unsigned short (*lB)[40] = (unsigned short (*)[40])(smem + 128 * 40);
    unsigned short (*stage)[72] = (unsigned short (*)[72])smem;
    const int t = threadIdx.x;
    const int lane = t & 63, wid = t >> 6;
    const int wm = wid >> 1, wn = wid & 1;
    const int lrow = lane & 15, quad = lane >> 4;
    const int mode = blockIdx.x >> 1;
    const int ob = (blockIdx.x & 1) * 128;
    const int n0 = blockIdx.y * 128;
    const int b  = blockIdx.z;
    const unsigned short* W  = (mode == 0) ? Wq : (mode == 1) ? Wk : Wv;
    const float* bias        = (mode == 0) ? bq : (mode == 1) ? bk : bv;
    const unsigned short* XT = (mode == 0) ? xT : srcT;
    unsigned short* out      = (mode == 0) ? qo : (mode == 1) ? ko : vo;

    const int srow[2] = { (0*256 + t) >> 2, (1*256 + t) >> 2 };
    const int scg = (t & 3) * 8;

    floatx4 acc[4][4];
#pragma unroll
    for (int i = 0; i < 4; ++i)
#pragma unroll
        for (int j = 0; j < 4; ++j) acc[i][j] = (floatx4){0.f,0.f,0.f,0.f};

    bf16x8 rW[2], rX[2];
#pragma unroll
    for (int r = 0; r < 2; ++r) {
        rW[r] = *(const bf16x8*)&W[(size_t)(ob + srow[r]) * 256 + scg];
        rX[r] = *(const bf16x8*)&XT[((size_t)b * SEQ + n0 + srow[r]) * 256 + scg];
    }
#pragma unroll
    for (int r = 0; r < 2; ++r) {
        *(bf16x8*)&lA[srow[r]][scg] = rW[r];
        *(bf16x8*)&lB[srow[r]][scg] = rX[r];
    }
    __syncthreads();

    for (int kc = 0; kc < 8; ++kc) {
        const bool pre = (kc + 1 < 8);
        if (pre) {
            const int k1 = (kc + 1) * 32;
#pragma unroll
            for (int r = 0; r < 2; ++r) {
                rW[r] = *(const bf16x8*)&W[(size_t)(ob + srow[r]) * 256 + k1 + scg];
                rX[r] = *(const bf16x8*)&XT[((size_t)b * SEQ + n0 + srow[r]) * 256 + k1 + scg];
            }
        }
        bf16x8 aF[4], bF[4];
        const int kq = quad * 8;
#pragma unroll
        for (int mt = 0; mt < 4; ++mt)
            aF[mt] = *(const bf16x8*)&lA[wm*64 + mt*16 + lrow][kq];
#pragma unroll
        for (int nt = 0; nt < 4; ++nt)
            bF[nt] = *(const bf16x8*)&lB[wn*64 + nt*16 + lrow][kq];
#pragma unroll
        for (int mt = 0; mt < 4; ++mt)
#pragma unroll
            for (int nt = 0; nt < 4; ++nt)
                acc[mt][nt] = MFMA(aF[mt], bF[nt], acc[mt][nt]);
        __syncthreads();
        if (pre) {
#pragma unroll
            for (int r = 0; r < 2; ++r) {
                *(bf16x8*)&lA[srow[r]][scg] = rW[r];
                *(bf16x8*)&lB[srow[r]][scg] = rX[r];
            }
            __syncthreads();
        }
    }
    const float osc = (mode == 0) ? SCALE_LOG2 : 1.0f;
    if (mode == 2) {
#pragma unroll
        for (int mt = 0; mt < 4; ++mt) {
#pragma unroll
            for (int j = 0; j < 4; ++j) {
                int o = ob + wm*64 + mt*16 + quad*4 + j;
                float bvv = bias[o];
                int d = o >> 2, h = o & 3;
#pragma unroll
                for (int nt = 0; nt < 4; ++nt) {
                    int n = n0 + wn*64 + nt*16 + lrow;
                    out[((size_t)(b*HEADS + h) * HD + d) * SEQ + n] = f2bf(acc[mt][nt][j] + bvv);
                }
            }
        }
        return;
    }
    for (int half = 0; half < 2; ++half) {
        __syncthreads();
        if (wm == half) {
#pragma unroll
            for (int mt = 0; mt < 4; ++mt)
#pragma unroll
                for (int j = 0; j < 4; ++j) {
                    int o = ob + half*64 + mt*16 + quad*4 + j;
                    float bvv = bias[o];
                    int col = j*16 + mt*4 + quad;
#pragma unroll
                    for (int nt = 0; nt < 4; ++nt) {
                        int n = wn*64 + nt*16 + lrow;
                        stage[n][col] = f2bf((acc[mt][nt][j] + bvv) * osc);
                    }
                }
        }
        __syncthreads();
#pragma unroll
        for (int i = 0; i < 4; ++i) {
            int c = i * 256 + t;
            int n = c >> 3, h = (c >> 1) & 3, sub = c & 1;
            bf16x8 val = *(const bf16x8*)&stage[n][h*16 + sub*8];
            int d0 = (ob >> 2) + half*16 + sub*8;
            *(bf16x8*)&out[((size_t)(b*HEADS + h) * SEQ + n0 + n) * HD + d0] = val;
        }
    }
}

// ---------------------------------------------------------------------------
// Flash attention, transposed-softmax, m-split, double-buffered LDS.
// grid (32, SEQ/128): blockIdx.x = chunk*16+bh (XCD swizzle), blockIdx.y = qt.
// Native v_exp_f32 (EXP2); denominator via all-ones-A MFMA; poO bf16.
// ---------------------------------------------------------------------------
__global__ __launch_bounds__(256, 4) void flash_attn(
        const unsigned short* __restrict__ q,
        const unsigned short* __restrict__ k,
        const unsigned short* __restrict__ v,
        unsigned short* __restrict__ poO, float* __restrict__ pol)
{
    __shared__ unsigned short smem[2][9216];   // per buf: lK 64x72 then lV 64x72
    const int t = threadIdx.x, lane = t & 63, wid = t >> 6;
    const int lrow = lane & 15, quad = lane >> 4;
    const int bc = blockIdx.x, qt = blockIdx.y;
    const int bh = bc & 15, chunk = bc >> 4;
    const int hb = (bh & 3) * BATCH + (bh >> 2);
    const int r0 = qt * 128 + wid * 32;

    bf16x8 qf[2][2];
#pragma unroll
    for (int nh = 0; nh < 2; ++nh) {
        const size_t base = ((size_t)bh * SEQ + r0 + nh*16 + lrow) * HD;
        qf[nh][0] = *(const bf16x8*)&q[base + quad * 8];
        qf[nh][1] = *(const bf16x8*)&q[base + 32 + quad * 8];
    }
    bf16x8 ones;
#pragma unroll
    for (int i = 0; i < 8; ++i) ones[i] = (short)0x3F80;  // bf16 1.0
    int mmv[2], cgv[2], krv[2];
#pragma unroll
    for (int r = 0; r < 2; ++r) {
        int linear = r * 256 + t;
        int mm = linear >> 3, cg = (linear & 7) * 8;
        int c2 = mm >> 5, mp = mm & 31;
        mmv[r] = mm; cgv[r] = cg;
        krv[r] = (c2 << 5) + ((mp & 4) << 2) + ((mp >> 3) << 2) + (mp & 3);
    }
    const size_t kbase = ((size_t)bh * SEQ + chunk * (SEQ/MCHUNKS));
    const size_t vbase = (size_t)bh * HD;
    const int moff = chunk * (SEQ/MCHUNKS);
    const int NIT = SEQ / MCHUNKS / 64;

    floatx4 oacc[2][4], oaccL[2];
#pragma unroll
    for (int nh = 0; nh < 2; ++nh) {
        oaccL[nh] = (floatx4){0.f,0.f,0.f,0.f};
#pragma unroll
        for (int i = 0; i < 4; ++i) oacc[nh][i] = (floatx4){0.f,0.f,0.f,0.f};
    }

    {
        bf16x8 pk[2], pv[2];
#pragma unroll
        for (int r = 0; r < 2; ++r) {
            pk[r] = *(const bf16x8*)&k[(kbase + mmv[r]) * HD + cgv[r]];
            pv[r] = *(const bf16x8*)&v[(vbase + mmv[r]) * SEQ + moff + cgv[r]];
        }
#pragma unroll
        for (int r = 0; r < 2; ++r) {
            *(bf16x8*)&smem[0][krv[r]*72 + cgv[r]]        = pk[r];
            *(bf16x8*)&smem[0][4608 + mmv[r]*72 + cgv[r]] = pv[r];
        }
    }
    __syncthreads();

    int p = 0;
#pragma unroll 1
    for (int it = 0; it < NIT; ++it) {
        bf16x8 pk[2], pv[2];
        const bool pre = (it + 1 < NIT);
        if (pre) {
            const int m1 = (it + 1) * 64;
#pragma unroll
            for (int r = 0; r < 2; ++r) {
                pk[r] = *(const bf16x8*)&k[(kbase + m1 + mmv[r]) * HD + cgv[r]];
                pv[r] = *(const bf16x8*)&v[(vbase + mmv[r]) * SEQ + moff + m1 + cgv[r]];
            }
        }
        const unsigned short* lK = smem[p];
        const unsigned short* lV = smem[p] + 4608;

        bf16x8 pf8[2][2];
#pragma unroll
        for (int c2 = 0; c2 < 2; ++c2) {
            floatx4 sa[2][2];
#pragma unroll
            for (int AB = 0; AB < 2; ++AB) {
                sa[AB][0] = (floatx4){0.f,0.f,0.f,0.f};
                sa[AB][1] = (floatx4){0.f,0.f,0.f,0.f};
#pragma unroll
                for (int kc = 0; kc < 2; ++kc) {
                    bf16x8 kf = *(const bf16x8*)&lK[(c2*32 + AB*16 + lrow)*72 + kc*32 + quad*8];
                    sa[AB][0] = MFMA(kf, qf[0][kc], sa[AB][0]);
                    sa[AB][1] = MFMA(kf, qf[1][kc], sa[AB][1]);
                }
            }
#pragma unroll
            for (int nh = 0; nh < 2; ++nh) {
                floatx4 ea, eb;
#pragma unroll
                for (int i = 0; i < 4; ++i) { ea[i] = EXP2(sa[0][nh][i]); eb[i] = EXP2(sa[1][nh][i]); }
                pf8[c2][nh] = pack_bf16x8(ea, eb);
            }
        }
#pragma unroll
        for (int c2 = 0; c2 < 2; ++c2) {
            oaccL[0] = MFMA(ones, pf8[c2][0], oaccL[0]);
            oaccL[1] = MFMA(ones, pf8[c2][1], oaccL[1]);
#pragma unroll
            for (int dt = 0; dt < 4; ++dt) {
                bf16x8 vf = *(const bf16x8*)&lV[(dt*16 + lrow)*72 + c2*32 + quad*8];
                oacc[0][dt] = MFMA(vf, pf8[c2][0], oacc[0][dt]);
                oacc[1][dt] = MFMA(vf, pf8[c2][1], oacc[1][dt]);
            }
        }
        if (pre) {
#pragma unroll
            for (int r = 0; r < 2; ++r) {
                *(bf16x8*)&smem[p^1][krv[r]*72 + cgv[r]]        = pk[r];
                *(bf16x8*)&smem[p^1][4608 + mmv[r]*72 + cgv[r]] = pv[r];
            }
        }
        __syncthreads();
        p ^= 1;
    }
    const size_t prow = (size_t)(chunk*16 + hb) * SEQ + qt * 128;
    if (lane < 16) {
        pol[prow + wid*32 + lrow]      = oaccL[0][0];
        pol[prow + wid*32 + 16 + lrow] = oaccL[1][0];
    }
    unsigned short* stB = (unsigned short*)&smem[0][0];   // [128][72] bf16
#pragma unroll
    for (int nh = 0; nh < 2; ++nh)
#pragma unroll
        for (int dt = 0; dt < 4; ++dt)
#pragma unroll
            for (int j = 0; j < 4; ++j)
                stB[(wid*32 + nh*16 + lrow)*72 + dt*16 + quad*4 + j] = f2bf(oacc[nh][dt][j]);
    __syncthreads();
#pragma unroll
    for (int i = 0; i < 4; ++i) {
        int c = i * 256 + t;
        int row = c >> 3, sub = c & 7;
        *(bf16x8*)&poO[(prow + row) * HD + sub*8] = *(const bf16x8*)&stB[row*72 + sub*8];
    }
}

// ---------------------------------------------------------------------------
// mlp1 (merge folded, LDS dbuf, 256-wide o-tiles to halve redundant A reads):
// h1[pos][512] = xT@w1b[:,0:256]^T + attnC'@w1f^T + b1f; attnC' combined on
// the fly from bf16 poO partials + pol.  Fused BN stats atomics.
// grid (2, NPOS/64), block 256.  LDS 52 KB -> 3 blocks/CU.
// ---------------------------------------------------------------------------
__global__ __launch_bounds__(256) void gemm_mlp1(
        const unsigned short* __restrict__ xT, const unsigned short* __restrict__ poO,
        const float* __restrict__ pol,
        const unsigned short* __restrict__ w1b, const unsigned short* __restrict__ w1f,
        const float* __restrict__ b1f, unsigned short* __restrict__ h1,
        float* __restrict__ sums, float* __restrict__ sumsq)
{
    __shared__ unsigned short lA[2][64][40];
    __shared__ unsigned short lB[2][256][40];
    __shared__ float sInv[256];
    const int t = threadIdx.x;
    const int lane = t & 63, wid = t >> 6;
    const int wm = wid >> 1, wn = wid & 1;
    const int lrow = lane & 15, quad = lane >> 4;
    const int o0 = blockIdx.x * 256;
    const int p0 = blockIdx.y * 64;
    const int b = p0 >> 12, n0 = p0 & (SEQ - 1);
    const size_t CH = (size_t)16 * SEQ * HD;

    {
        int h = t >> 6, nn = t & 63;
        int hb = h * BATCH + b;
        float l0 = pol[(size_t)hb * SEQ + n0 + nn];
        float l1 = pol[(size_t)(16 + hb) * SEQ + n0 + nn];
        sInv[t] = 1.0f / (l0 + l1);
    }
    __syncthreads();

    const int arow = t >> 2, acg = (t & 3) * 8;
    const int brow[4] = { t >> 2, (256 + t) >> 2, (512 + t) >> 2, (768 + t) >> 2 };

    floatx4 acc[2][8];
#pragma unroll
    for (int i = 0; i < 2; ++i)
#pragma unroll
        for (int j = 0; j < 8; ++j) acc[i][j] = (floatx4){0.f,0.f,0.f,0.f};

    bf16x8 rA, rB[4];
    auto load_tile = [&](int k0) {
        if (k0 < 256) {
            rA = *(const bf16x8*)&xT[(size_t)(p0 + arow) * 256 + k0 + acg];
#pragma unroll
            for (int r = 0; r < 4; ++r)
                rB[r] = *(const bf16x8*)&w1b[(size_t)(o0 + brow[r]) * 512 + k0 + acg];
        } else {
            const int kk2 = k0 - 256;
            const int h = kk2 >> 6, d0 = kk2 & 63, hb = h * BATCH + b;
            const unsigned short* bse = &poO[((size_t)hb * SEQ + n0 + arow) * HD + d0 + acg];
            bf16x8 a0 = *(const bf16x8*)bse;
            bf16x8 a1 = *(const bf16x8*)(bse + CH);
            float inv = sInv[h*64 + arow];
            unsigned short res[8];
#pragma unroll
            for (int i = 0; i < 8; ++i)
                res[i] = f2bf((bf2f((unsigned short)a0[i]) + bf2f((unsigned short)a1[i])) * inv);
            rA = *(const bf16x8*)res;
#pragma unroll
            for (int r = 0; r < 4; ++r)
                rB[r] = *(const bf16x8*)&w1f[(size_t)(o0 + brow[r]) * 256 + kk2 + acg];
        }
    };

    load_tile(0);
    *(bf16x8*)&lA[0][arow][acg] = rA;
#pragma unroll
    for (int r = 0; r < 4; ++r) *(bf16x8*)&lB[0][brow[r]][acg] = rB[r];
    __syncthreads();

    int p = 0;
    for (int kc = 0; kc < 16; ++kc) {
        const bool pre = (kc + 1 < 16);
        if (pre) load_tile((kc + 1) * 32);
        bf16x8 aF[2], bF[8];
        const int kq = quad * 8;
#pragma unroll
        for (int mt = 0; mt < 2; ++mt)
            aF[mt] = *(const bf16x8*)&lA[p][wm*32 + mt*16 + lrow][kq];
#pragma unroll
        for (int nt = 0; nt < 8; ++nt)
            bF[nt] = *(const bf16x8*)&lB[p][wn*128 + nt*16 + lrow][kq];
#pragma unroll
        for (int mt = 0; mt < 2; ++mt)
#pragma unroll
            for (int nt = 0; nt < 8; ++nt)
                acc[mt][nt] = MFMA(aF[mt], bF[nt], acc[mt][nt]);
        if (pre) {
            *(bf16x8*)&lA[p^1][arow][acg] = rA;
#pragma unroll
            for (int r = 0; r < 4; ++r) *(bf16x8*)&lB[p^1][brow[r]][acg] = rB[r];
        }
        __syncthreads();
        p ^= 1;
    }
#pragma unroll
    for (int nt = 0; nt < 8; ++nt) {
        int o = o0 + wn*128 + nt*16 + lrow;
        float bvv = b1f[o];
        float s = 0.f, qs = 0.f;
#pragma unroll
        for (int mt = 0; mt < 2; ++mt)
#pragma unroll
            for (int j = 0; j < 4; ++j) {
                int pos = p0 + wm*32 + mt*16 + quad*4 + j;
                float val = acc[mt][nt][j] + bvv;
                h1[(size_t)pos * 512 + o] = f2bf(val);
                s += val; qs += val * val;
            }
        s  += __shfl_xor(s, 16);  s  += __shfl_xor(s, 32);
        qs += __shfl_xor(qs, 16); qs += __shfl_xor(qs, 32);
        if (lane < 16) {
            atomicAdd(&sums[o], s);
            atomicAdd(&sumsq[o], qs);
        }
    }
}

// ---------------------------------------------------------------------------
// mlp2 (bf16 W, inline bn_final, LDS double-buffered):
// out[b][o][n] f32 = W2 @ relu(bn(h1))^T + bias. grid (2, NPOS/64).
// ---------------------------------------------------------------------------
__global__ __launch_bounds__(256) void gemm_mlp2(
        const unsigned short* __restrict__ W2, const unsigned short* __restrict__ h1,
        const float* __restrict__ bias,
        const float* __restrict__ sums, const float* __restrict__ sumsq,
        const float* __restrict__ gamma, const float* __restrict__ beta,
        float* __restrict__ out)
{
    __shared__ unsigned short lA[2][128][40];
    __shared__ unsigned short lB[2][64][40];
    __shared__ float sSc[512], sSh[512];
    const int t = threadIdx.x;
    const int lane = t & 63, wid = t >> 6;
    const int wm = wid >> 1, wn = wid & 1;
    const int lrow = lane & 15, quad = lane >> 4;
    const int o0 = blockIdx.x * 128;
    const int p0 = blockIdx.y * 64;

#pragma unroll
    for (int cc = 0; cc < 2; ++cc) {
        int c = cc * 256 + t;
        float mean = sums[c] * (1.0f / NPOS);
        float var  = sumsq[c] * (1.0f / NPOS) - mean * mean;
        float sc = gamma[c] * rsqrtf(var + 1e-5f);
        sSc[c] = sc;
        sSh[c] = beta[c] - mean * sc;
    }
    __syncthreads();

    const int arow[2] = { (0*256 + t) >> 2, (1*256 + t) >> 2 };
    const int acg = (t & 3) * 8;
    const int brow = t >> 2;

    floatx4 acc[4][2];
#pragma unroll
    for (int i = 0; i < 4; ++i)
#pragma unroll
        for (int j = 0; j < 2; ++j) acc[i][j] = (floatx4){0.f,0.f,0.f,0.f};

    bf16x8 rW[2], rH;
    auto load_tile = [&](int k0) {
#pragma unroll
        for (int r = 0; r < 2; ++r)
            rW[r] = *(const bf16x8*)&W2[(size_t)(o0 + arow[r]) * 512 + k0 + acg];
        bf16x8 hv = *(const bf16x8*)&h1[(size_t)(p0 + brow) * 512 + k0 + acg];
        unsigned short res[8];
#pragma unroll
        for (int i = 0; i < 8; ++i) {
            int c = k0 + acg + i;
            float f = bf2f((unsigned short)hv[i]);
            f = fmaxf(f * sSc[c] + sSh[c], 0.f);
            res[i] = f2bf(f);
        }
        rH = *(const bf16x8*)res;
    };

    load_tile(0);
#pragma unroll
    for (int r = 0; r < 2; ++r) *(bf16x8*)&lA[0][arow[r]][acg] = rW[r];
    *(bf16x8*)&lB[0][brow][acg] = rH;
    __syncthreads();

    int p = 0;
    for (int kc = 0; kc < 16; ++kc) {
        const bool pre = (kc + 1 < 16);
        if (pre) load_tile((kc + 1) * 32);
        bf16x8 aF[4], bF[2];
        const int kq = quad * 8;
#pragma unroll
        for (int mt = 0; mt < 4; ++mt)
            aF[mt] = *(const bf16x8*)&lA[p][wm*64 + mt*16 + lrow][kq];
#pragma unroll
        for (int nt = 0; nt < 2; ++nt)
            bF[nt] = *(const bf16x8*)&lB[p][wn*32 + nt*16 + lrow][kq];
#pragma unroll
        for (int mt = 0; mt < 4; ++mt)
#pragma unroll
            for (int nt = 0; nt < 2; ++nt)
                acc[mt][nt] = MFMA(aF[mt], bF[nt], acc[mt][nt]);
        if (pre) {
#pragma unroll
            for (int r = 0; r < 2; ++r) *(bf16x8*)&lA[p^1][arow[r]][acg] = rW[r];
            *(bf16x8*)&lB[p^1][brow][acg] = rH;
        }
        __syncthreads();
        p ^= 1;
    }
#pragma unroll
    for (int mt = 0; mt < 4; ++mt)
#pragma unroll
        for (int j = 0; j < 4; ++j) {
            int o = o0 + wm*64 + mt*16 + quad*4 + j;
            float bvv = bias[o];
#pragma unroll
            for (int nt = 0; nt < 2; ++nt) {
                int pos = p0 + wn*32 + nt*16 + lrow;
                int b = pos >> 12, n = pos & (SEQ - 1);
                out[((size_t)b * D_MODEL + o) * SEQ + n] = acc[mt][nt][j] + bvv;
            }
        }
}

// ---------------------------------------------------------------------------
extern "C" void kernel_launch(void* const* d_in, const int* in_sizes, int n_in,
                              void* d_out, int out_size, void* d_ws, size_t ws_size,
                              hipStream_t stream)
{
    (void)in_sizes; (void)n_in; (void)out_size; (void)ws_size;
    const float* x        = (const float*)d_in[0];
    const float* source   = (const float*)d_in[1];
    const float* pq_w     = (const float*)d_in[2];
    const float* pq_b     = (const float*)d_in[3];
    const float* pk_w     = (const float*)d_in[4];
    const float* pk_b     = (const float*)d_in[5];
    const float* pv_w     = (const float*)d_in[6];
    const float* pv_b     = (const float*)d_in[7];
    const float* merge_w  = (const float*)d_in[8];
    const float* merge_b  = (const float*)d_in[9];
    const float* mlp1_w   = (const float*)d_in[10];
    const float* mlp1_b   = (const float*)d_in[11];
    const float* bn_gamma = (const float*)d_in[12];
    const float* bn_beta  = (const float*)d_in[13];
    const float* mlp2_w   = (const float*)d_in[14];
    const float* mlp2_b   = (const float*)d_in[15];
    float* out = (float*)d_out;

    char* ws = (char*)d_ws;
    const size_t MB = 1ull << 20;
    unsigned short* xT   = (unsigned short*)(ws);             //  8 MB [pos][256]
    unsigned short* srcT = (unsigned short*)(ws + 8*MB);      //  8 MB [pos][256]
    unsigned short* q    = (unsigned short*)(ws + 16*MB);     //  8 MB [bh][n][64]
    unsigned short* kk   = (unsigned short*)(ws + 24*MB);     //  8 MB [bh][m][64]
    unsigned short* v    = (unsigned short*)(ws + 32*MB);     //  8 MB [bh][64][m]
    unsigned short* poO  = (unsigned short*)(ws + 40*MB);     // 16 MB bf16 partial O
    unsigned short* h1   = (unsigned short*)(ws + 57*MB);     // 16 MB [pos][512]
    float* pol = (float*)(ws + 73*MB);                        // 512 KB partial l
    unsigned short* wqb = (unsigned short*)(ws + 74*MB);
    unsigned short* wkb = wqb + 65536;
    unsigned short* wvb = wkb + 65536;
    unsigned short* wmt = wvb + 65536;                        // [c'][o] 128 KB
    unsigned short* w1b = wmt + 65536;                        // 512 KB full mlp1_w
    unsigned short* w2b = w1b + 262144;                       // 256 KB
    unsigned short* w1f = w2b + 131072;                       // 256 KB folded
    float* b1f = (float*)(w1f + 131072);                      // 512 folded bias
    float* bn_sum = b1f + 512;
    float* bn_sumsq = bn_sum + 512;

    hipMemsetAsync(bn_sum, 0, 1024 * sizeof(float), stream);

    prep<<<dim3(1152), 256, 0, stream>>>(
        pq_w, pk_w, pv_w, merge_w, mlp1_w, mlp2_w, x, source,
        wqb, wkb, wvb, wmt, w1b, w2b, xT, srcT);
    prep2<<<dim3(2, 9), 256, 0, stream>>>(mlp1_w, mlp1_b, merge_b, wmt, w1f, b1f);
    proj_qkv_all<<<dim3(6, SEQ/128, BATCH), 256, 0, stream>>>(
        wqb, pq_b, wkb, pk_b, wvb, pv_b, xT, srcT, q, kk, v);
    flash_attn<<<dim3(16*MCHUNKS, SEQ/128), 256, 0, stream>>>(q, kk, v, poO, pol);
    gemm_mlp1<<<dim3(2, NPOS/64), 256, 0, stream>>>(
        xT, poO, pol, w1b, w1f, b1f, h1, bn_sum, bn_sumsq);
    gemm_mlp2<<<dim3(2, NPOS/64), 256, 0, stream>>>(
        w2b, h1, mlp2_b, bn_sum, bn_sumsq, bn_gamma, bn_beta, out);
}

// Round 9
// 273.069 us; speedup vs baseline: 1.1684x; 1.0178x over previous
//
#include <hip/hip_runtime.h>
#include <hip/hip_bf16.h>

#define D_MODEL 256
#define HEADS 4
#define HD 64
#define BATCH 4
#define SEQ 4096
#define NPOS (BATCH*SEQ)          // 16384 positions
#define SCALE_LOG2 0.18033688011112042f  // log2(e)/8, folded into q projection
#define MCHUNKS 2                 // flash m-split (partials add; no online max)

typedef __attribute__((ext_vector_type(4))) float floatx4;
typedef __attribute__((ext_vector_type(8))) short bf16x8;
typedef __attribute__((ext_vector_type(4))) short bf16x4;
typedef __attribute__((ext_vector_type(4))) unsigned short ushortx4;

__device__ __forceinline__ float bf2f(unsigned short b) {
    return __uint_as_float(((unsigned int)b) << 16);
}
__device__ __forceinline__ unsigned short f2bf(float f) {
    unsigned int u = __float_as_uint(f);
    return (unsigned short)((u + 0x7fffu + ((u >> 16) & 1u)) >> 16);
}
__device__ __forceinline__ bf16x4 pack_bf16x4(float a, float b, float c, float d) {
    __hip_bfloat162 lo = __float22bfloat162_rn(float2{a, b});
    __hip_bfloat162 hi = __float22bfloat162_rn(float2{c, d});
    union { __hip_bfloat162 h2[2]; bf16x4 v; } u;
    u.h2[0] = lo; u.h2[1] = hi;
    return u.v;
}
__device__ __forceinline__ bf16x8 pack_bf16x8(floatx4 a, floatx4 b) {
    union { bf16x4 h[2]; bf16x8 v; } u;
    u.h[0] = pack_bf16x4(a[0], a[1], a[2], a[3]);
    u.h[1] = pack_bf16x4(b[0], b[1], b[2], b[3]);
    return u.v;
}
#define MFMA(a,b,c) __builtin_amdgcn_mfma_f32_16x16x32_bf16((a),(b),(c),0,0,0)
#define EXP2(x) __builtin_amdgcn_exp2f(x)   // native v_exp_f32 (exp2f -> ocml is ~5x slower)

// ---------------------------------------------------------------------------
// prep: blocks [0,576): linear f32->bf16 weight copies (pq,pk,pv,mlp1,mlp2).
//       blocks [576,640): Wmt[c'][o] = merge_w[o][(c'&63)*4 + (c'>>6)].
//       blocks [640,1152): transpose x/source -> xT/srcT [pos][256] bf16.
// ---------------------------------------------------------------------------
__global__ __launch_bounds__(256) void prep(
        const float* __restrict__ pq_w, const float* __restrict__ pk_w,
        const float* __restrict__ pv_w, const float* __restrict__ merge_w,
        const float* __restrict__ mlp1_w, const float* __restrict__ mlp2_w,
        const float* __restrict__ x, const float* __restrict__ src,
        unsigned short* __restrict__ wqb, unsigned short* __restrict__ wkb,
        unsigned short* __restrict__ wvb, unsigned short* __restrict__ wmt,
        unsigned short* __restrict__ w1b, unsigned short* __restrict__ w2b,
        unsigned short* __restrict__ xT, unsigned short* __restrict__ srcT)
{
    __shared__ unsigned short lT[64][264];
    const int t = threadIdx.x;
    const int bx = blockIdx.x;
    if (bx < 576) {
        int linear = bx * 1024 + t * 4;
        const float* srcW; unsigned short* dst; int off;
        if (linear < 65536)       { srcW = pq_w;   dst = wqb; off = 0; }
        else if (linear < 131072) { srcW = pk_w;   dst = wkb; off = 65536; }
        else if (linear < 196608) { srcW = pv_w;   dst = wvb; off = 131072; }
        else if (linear < 458752) { srcW = mlp1_w; dst = w1b; off = 196608; }
        else                      { srcW = mlp2_w; dst = w2b; off = 458752; }
        int i = linear - off;
        float4 w = *(const float4*)&srcW[i];
        ushortx4 s = { f2bf(w.x), f2bf(w.y), f2bf(w.z), f2bf(w.w) };
        *(ushortx4*)&dst[i] = s;
        return;
    }
    if (bx < 640) {
        int i = (bx - 576) * 1024 + t * 4;
        int cp = i >> 8, o = i & 255;
        int pc = ((cp & 63) << 2) | (cp >> 6);
        unsigned short s[4];
#pragma unroll
        for (int j = 0; j < 4; ++j)
            s[j] = f2bf(merge_w[(size_t)(o + j) * 256 + pc]);
        *(ushortx4*)&wmt[i] = *(const ushortx4*)s;
        return;
    }
    int z = bx - 640;
    const float* X = (z < 256) ? x : src;
    unsigned short* O = (z < 256) ? xT : srcT;
    int rem = z & 255;
    int b = rem >> 6, n0 = (rem & 63) * 64;
#pragma unroll
    for (int r = 0; r < 16; ++r) {
        int idx = r * 256 + t;
        int ch = idx >> 4, nnq = (idx & 15) * 4;
        float4 v4 = *(const float4*)&X[((size_t)b * 256 + ch) * SEQ + n0 + nnq];
        lT[nnq + 0][ch] = f2bf(v4.x);
        lT[nnq + 1][ch] = f2bf(v4.y);
        lT[nnq + 2][ch] = f2bf(v4.z);
        lT[nnq + 3][ch] = f2bf(v4.w);
    }
    __syncthreads();
#pragma unroll
    for (int r = 0; r < 8; ++r) {
        int idx = r * 256 + t;
        int row = idx >> 5, cg = (idx & 31) * 8;
        *(bf16x8*)&O[((size_t)b * SEQ + n0 + row) * 256 + cg] = *(const bf16x8*)&lT[row][cg];
    }
}

// ---------------------------------------------------------------------------
// prep2: fold merge into mlp1.  y<8: w1f[o2][c'] = sum_o W1b[o2][o]*Wmt[c'][o];
// y==8: b1f[o2] = mlp1_b[o2] + sum_o W1b[o2][o]*merge_b[o].  grid (2,9).
// ---------------------------------------------------------------------------
__global__ __launch_bounds__(256) void prep2(
        const float* __restrict__ mlp1_w, const float* __restrict__ mlp1_b,
        const float* __restrict__ merge_b, const unsigned short* __restrict__ wmt,
        unsigned short* __restrict__ w1f, float* __restrict__ b1f)
{
    __shared__ unsigned short lA[64][40];
    __shared__ unsigned short lB[128][40];
    const int t = threadIdx.x;
    if (blockIdx.y == 8) {
        int o2 = blockIdx.x * 256 + t;
        float s = mlp1_b[o2];
        for (int o = 0; o < 256; ++o)
            s += mlp1_w[(size_t)o2 * 512 + 256 + o] * merge_b[o];
        b1f[o2] = s;
        return;
    }
    const int lane = t & 63, wid = t >> 6;
    const int wm = wid >> 1, wn = wid & 1;
    const int lrow = lane & 15, quad = lane >> 4;
    const int o20 = blockIdx.y * 64;
    const int c0  = blockIdx.x * 128;

    floatx4 acc[2][4];
#pragma unroll
    for (int i = 0; i < 2; ++i)
#pragma unroll
        for (int j = 0; j < 4; ++j) acc[i][j] = (floatx4){0.f,0.f,0.f,0.f};

    for (int k0 = 0; k0 < 256; k0 += 32) {
#pragma unroll
        for (int r = 0; r < 2; ++r) {
            int linear = r * 1024 + t * 4;
            int row = linear >> 5, col = linear & 31;
            float4 w = *(const float4*)&mlp1_w[(size_t)(o20 + row) * 512 + 256 + k0 + col];
            ushortx4 s = { f2bf(w.x), f2bf(w.y), f2bf(w.z), f2bf(w.w) };
            *(ushortx4*)&lA[row][col] = s;
        }
#pragma unroll
        for (int r = 0; r < 2; ++r) {
            int linear = r * 256 + t;
            int row = linear >> 2, cg = (linear & 3) * 8;
            *(bf16x8*)&lB[row][cg] = *(const bf16x8*)&wmt[(size_t)(c0 + row) * 256 + k0 + cg];
        }
        __syncthreads();
        bf16x8 aF[2], bF[4];
        const int kq = quad * 8;
#pragma unroll
        for (int mt = 0; mt < 2; ++mt)
            aF[mt] = *(const bf16x8*)&lA[wm*32 + mt*16 + lrow][kq];
#pragma unroll
        for (int nt = 0; nt < 4; ++nt)
            bF[nt] = *(const bf16x8*)&lB[wn*64 + nt*16 + lrow][kq];
#pragma unroll
        for (int mt = 0; mt < 2; ++mt)
#pragma unroll
            for (int nt = 0; nt < 4; ++nt)
                acc[mt][nt] = MFMA(aF[mt], bF[nt], acc[mt][nt]);
        __syncthreads();
    }
#pragma unroll
    for (int nt = 0; nt < 4; ++nt) {
        int cp = c0 + wn*64 + nt*16 + lrow;
#pragma unroll
        for (int mt = 0; mt < 2; ++mt)
#pragma unroll
            for (int j = 0; j < 4; ++j) {
                int o2 = o20 + wm*32 + mt*16 + quad*4 + j;
                w1f[(size_t)o2 * 256 + cp] = f2bf(acc[mt][nt][j]);
            }
    }
}

// ---------------------------------------------------------------------------
// Merged QKV projection with register-prefetch pipeline.
// grid (6, SEQ/128, B): mode = x>>1 (0=q,1=k,2=v), ob = (x&1)*128.
// ---------------------------------------------------------------------------
__global__ __launch_bounds__(256) void proj_qkv_all(
        const unsigned short* __restrict__ Wq, const float* __restrict__ bq,
        const unsigned short* __restrict__ Wk, const float* __restrict__ bk,
        const unsigned short* __restrict__ Wv, const float* __restrict__ bv,
        const unsigned short* __restrict__ xT, const unsigned short* __restrict__ srcT,
        unsigned short* __restrict__ qo, unsigned short* __restrict__ ko,
        unsigned short* __restrict__ vo)
{
    __shared__ unsigned short smem[128 * 80];
    unsigned short (*lA)[40] = (unsigned short (*)[40])smem;
    unsigned short (*lB)[40] = (unsigned short (*)[40])(smem + 128 * 40);
    unsigned short (*stage)[72] = (unsigned short (*)[72])smem;
    const int t = threadIdx.x;
    const int lane = t & 63, wid = t >> 6;
    const int wm = wid >> 1, wn = wid & 1;
    const int lrow = lane & 15, quad = lane >> 4;
    const int mode = blockIdx.x >> 1;
    const int ob = (blockIdx.x & 1) * 128;
    const int n0 = blockIdx.y * 128;
    const int b  = blockIdx.z;
    const unsigned short* W  = (mode == 0) ? Wq : (mode == 1) ? Wk : Wv;
    const float* bias        = (mode == 0) ? bq : (mode == 1) ? bk : bv;
    const unsigned short* XT = (mode == 0) ? xT : srcT;
    unsigned short* out      = (mode == 0) ? qo : (mode == 1) ? ko : vo;

    const int srow[2] = { (0*256 + t) >> 2, (1*256 + t) >> 2 };
    const int scg = (t & 3) * 8;

    floatx4 acc[4][4];
#pragma unroll
    for (int i = 0; i < 4; ++i)
#pragma unroll
        for (int j = 0; j < 4; ++j) acc[i][j] = (floatx4){0.f,0.f,0.f,0.f};

    bf16x8 rW[2], rX[2];
#pragma unroll
    for (int r = 0; r < 2; ++r) {
        rW[r] = *(const bf16x8*)&W[(size_t)(ob + srow[r]) * 256 + scg];
        rX[r] = *(const bf16x8*)&XT[((size_t)b * SEQ + n0 + srow[r]) * 256 + scg];
    }
#pragma unroll
    for (int r = 0; r < 2; ++r) {
        *(bf16x8*)&lA[srow[r]][scg] = rW[r];
        *(bf16x8*)&lB[srow[r]][scg] = rX[r];
    }
    __syncthreads();

    for (int kc = 0; kc < 8; ++kc) {
        const bool pre = (kc + 1 < 8);
        if (pre) {
            const int k1 = (kc + 1) * 32;
#pragma unroll
            for (int r = 0; r < 2; ++r) {
                rW[r] = *(const bf16x8*)&W[(size_t)(ob + srow[r]) * 256 + k1 + scg];
                rX[r] = *(const bf16x8*)&XT[((size_t)b * SEQ + n0 + srow[r]) * 256 + k1 + scg];
            }
        }
        bf16x8 aF[4], bF[4];
        const int kq = quad * 8;
#pragma unroll
        for (int mt = 0; mt < 4; ++mt)
            aF[mt] = *(const bf16x8*)&lA[wm*64 + mt*16 + lrow][kq];
#pragma unroll
        for (int nt = 0; nt < 4; ++nt)
            bF[nt] = *(const bf16x8*)&lB[wn*64 + nt*16 + lrow][kq];
#pragma unroll
        for (int mt = 0; mt < 4; ++mt)
#pragma unroll
            for (int nt = 0; nt < 4; ++nt)
                acc[mt][nt] = MFMA(aF[mt], bF[nt], acc[mt][nt]);
        __syncthreads();
        if (pre) {
#pragma unroll
            for (int r = 0; r < 2; ++r) {
                *(bf16x8*)&lA[srow[r]][scg] = rW[r];
                *(bf16x8*)&lB[srow[r]][scg] = rX[r];
            }
            __syncthreads();
        }
    }
    const float osc = (mode == 0) ? SCALE_LOG2 : 1.0f;
    if (mode == 2) {
#pragma unroll
        for (int mt = 0; mt < 4; ++mt) {
#pragma unroll
            for (int j = 0; j < 4; ++j) {
                int o = ob + wm*64 + mt*16 + quad*4 + j;
                float bvv = bias[o];
                int d = o >> 2, h = o & 3;
#pragma unroll
                for (int nt = 0; nt < 4; ++nt) {
                    int n = n0 + wn*64 + nt*16 + lrow;
                    out[((size_t)(b*HEADS + h) * HD + d) * SEQ + n] = f2bf(acc[mt][nt][j] + bvv);
                }
            }
        }
        return;
    }
    for (int half = 0; half < 2; ++half) {
        __syncthreads();
        if (wm == half) {
#pragma unroll
            for (int mt = 0; mt < 4; ++mt)
#pragma unroll
                for (int j = 0; j < 4; ++j) {
                    int o = ob + half*64 + mt*16 + quad*4 + j;
                    float bvv = bias[o];
                    int col = j*16 + mt*4 + quad;
#pragma unroll
                    for (int nt = 0; nt < 4; ++nt) {
                        int n = wn*64 + nt*16 + lrow;
                        stage[n][col] = f2bf((acc[mt][nt][j] + bvv) * osc);
                    }
                }
        }
        __syncthreads();
#pragma unroll
        for (int i = 0; i < 4; ++i) {
            int c = i * 256 + t;
            int n = c >> 3, h = (c >> 1) & 3, sub = c & 1;
            bf16x8 val = *(const bf16x8*)&stage[n][h*16 + sub*8];
            int d0 = (ob >> 2) + half*16 + sub*8;
            *(bf16x8*)&out[((size_t)(b*HEADS + h) * SEQ + n0 + n) * HD + d0] = val;
        }
    }
}

// ---------------------------------------------------------------------------
// Flash attention, transposed-softmax, m-split, double-buffered LDS.
// grid (32, SEQ/128): blockIdx.x = chunk*16+bh (XCD swizzle), blockIdx.y = qt.
// Native v_exp_f32; denominator via all-ones-A MFMA; poO bf16.
// Epilogue O^T staged with PACKED b64 LDS writes (u16 scatter was the source
// of the 8.5M bank-conflict cycles — R8 post-mortem).
// ---------------------------------------------------------------------------
__global__ __launch_bounds__(256, 4) void flash_attn(
        const unsigned short* __restrict__ q,
        const unsigned short* __restrict__ k,
        const unsigned short* __restrict__ v,
        unsigned short* __restrict__ poO, float* __restrict__ pol)
{
    __shared__ unsigned short smem[2][9216];   // per buf: lK 64x72 then lV 64x72
    const int t = threadIdx.x, lane = t & 63, wid = t >> 6;
    const int lrow = lane & 15, quad = lane >> 4;
    const int bc = blockIdx.x, qt = blockIdx.y;
    const int bh = bc & 15, chunk = bc >> 4;
    const int hb = (bh & 3) * BATCH + (bh >> 2);
    const int r0 = qt * 128 + wid * 32;

    bf16x8 qf[2][2];
#pragma unroll
    for (int nh = 0; nh < 2; ++nh) {
        const size_t base = ((size_t)bh * SEQ + r0 + nh*16 + lrow) * HD;
        qf[nh][0] = *(const bf16x8*)&q[base + quad * 8];
        qf[nh][1] = *(const bf16x8*)&q[base + 32 + quad * 8];
    }
    bf16x8 ones;
#pragma unroll
    for (int i = 0; i < 8; ++i) ones[i] = (short)0x3F80;  // bf16 1.0
    int mmv[2], cgv[2], krv[2];
#pragma unroll
    for (int r = 0; r < 2; ++r) {
        int linear = r * 256 + t;
        int mm = linear >> 3, cg = (linear & 7) * 8;
        int c2 = mm >> 5, mp = mm & 31;
        mmv[r] = mm; cgv[r] = cg;
        krv[r] = (c2 << 5) + ((mp & 4) << 2) + ((mp >> 3) << 2) + (mp & 3);
    }
    const size_t kbase = ((size_t)bh * SEQ + chunk * (SEQ/MCHUNKS));
    const size_t vbase = (size_t)bh * HD;
    const int moff = chunk * (SEQ/MCHUNKS);
    const int NIT = SEQ / MCHUNKS / 64;

    floatx4 oacc[2][4], oaccL[2];
#pragma unroll
    for (int nh = 0; nh < 2; ++nh) {
        oaccL[nh] = (floatx4){0.f,0.f,0.f,0.f};
#pragma unroll
        for (int i = 0; i < 4; ++i) oacc[nh][i] = (floatx4){0.f,0.f,0.f,0.f};
    }

    {
        bf16x8 pk[2], pv[2];
#pragma unroll
        for (int r = 0; r < 2; ++r) {
            pk[r] = *(const bf16x8*)&k[(kbase + mmv[r]) * HD + cgv[r]];
            pv[r] = *(const bf16x8*)&v[(vbase + mmv[r]) * SEQ + moff + cgv[r]];
        }
#pragma unroll
        for (int r = 0; r < 2; ++r) {
            *(bf16x8*)&smem[0][krv[r]*72 + cgv[r]]        = pk[r];
            *(bf16x8*)&smem[0][4608 + mmv[r]*72 + cgv[r]] = pv[r];
        }
    }
    __syncthreads();

    int p = 0;
#pragma unroll 1
    for (int it = 0; it < NIT; ++it) {
        bf16x8 pk[2], pv[2];
        const bool pre = (it + 1 < NIT);
        if (pre) {
            const int m1 = (it + 1) * 64;
#pragma unroll
            for (int r = 0; r < 2; ++r) {
                pk[r] = *(const bf16x8*)&k[(kbase + m1 + mmv[r]) * HD + cgv[r]];
                pv[r] = *(const bf16x8*)&v[(vbase + mmv[r]) * SEQ + moff + m1 + cgv[r]];
            }
        }
        const unsigned short* lK = smem[p];
        const unsigned short* lV = smem[p] + 4608;

        bf16x8 pf8[2][2];
#pragma unroll
        for (int c2 = 0; c2 < 2; ++c2) {
            floatx4 sa[2][2];
#pragma unroll
            for (int AB = 0; AB < 2; ++AB) {
                sa[AB][0] = (floatx4){0.f,0.f,0.f,0.f};
                sa[AB][1] = (floatx4){0.f,0.f,0.f,0.f};
#pragma unroll
                for (int kc = 0; kc < 2; ++kc) {
                    bf16x8 kf = *(const bf16x8*)&lK[(c2*32 + AB*16 + lrow)*72 + kc*32 + quad*8];
                    sa[AB][0] = MFMA(kf, qf[0][kc], sa[AB][0]);
                    sa[AB][1] = MFMA(kf, qf[1][kc], sa[AB][1]);
                }
            }
#pragma unroll
            for (int nh = 0; nh < 2; ++nh) {
                floatx4 ea, eb;
#pragma unroll
                for (int i = 0; i < 4; ++i) { ea[i] = EXP2(sa[0][nh][i]); eb[i] = EXP2(sa[1][nh][i]); }
                pf8[c2][nh] = pack_bf16x8(ea, eb);
            }
        }
#pragma unroll
        for (int c2 = 0; c2 < 2; ++c2) {
            oaccL[0] = MFMA(ones, pf8[c2][0], oaccL[0]);
            oaccL[1] = MFMA(ones, pf8[c2][1], oaccL[1]);
#pragma unroll
            for (int dt = 0; dt < 4; ++dt) {
                bf16x8 vf = *(const bf16x8*)&lV[(dt*16 + lrow)*72 + c2*32 + quad*8];
                oacc[0][dt] = MFMA(vf, pf8[c2][0], oacc[0][dt]);
                oacc[1][dt] = MFMA(vf, pf8[c2][1], oacc[1][dt]);
            }
        }
        if (pre) {
#pragma unroll
            for (int r = 0; r < 2; ++r) {
                *(bf16x8*)&smem[p^1][krv[r]*72 + cgv[r]]        = pk[r];
                *(bf16x8*)&smem[p^1][4608 + mmv[r]*72 + cgv[r]] = pv[r];
            }
        }
        __syncthreads();
        p ^= 1;
    }
    const size_t prow = (size_t)(chunk*16 + hb) * SEQ + qt * 128;
    if (lane < 16) {
        pol[prow + wid*32 + lrow]      = oaccL[0][0];
        pol[prow + wid*32 + 16 + lrow] = oaccL[1][0];
    }
    // epilogue: packed b64 stores (j=0..3 contiguous in d) — balanced banks
    unsigned short* stB = (unsigned short*)&smem[0][0];   // [128][72] bf16
#pragma unroll
    for (int nh = 0; nh < 2; ++nh)
#pragma unroll
        for (int dt = 0; dt < 4; ++dt) {
            bf16x4 pv4 = pack_bf16x4(oacc[nh][dt][0], oacc[nh][dt][1],
                                     oacc[nh][dt][2], oacc[nh][dt][3]);
            *(bf16x4*)&stB[(wid*32 + nh*16 + lrow)*72 + dt*16 + quad*4] = pv4;
        }
    __syncthreads();
#pragma unroll
    for (int i = 0; i < 4; ++i) {
        int c = i * 256 + t;
        int row = c >> 3, sub = c & 7;
        *(bf16x8*)&poO[(prow + row) * HD + sub*8] = *(const bf16x8*)&stB[row*72 + sub*8];
    }
}

// ---------------------------------------------------------------------------
// mlp1 (merge folded, LDS double-buffered, 1 barrier/iter, 128-o tiles):
// h1[pos][512] = xT@w1b[:,0:256]^T + attnC'@w1f^T + b1f;  attnC' combined
// on the fly from bf16 poO partials + pol.  Fused BN stats atomics.
// grid (4, NPOS/64), block 256.
// ---------------------------------------------------------------------------
__global__ __launch_bounds__(256) void gemm_mlp1(
        const unsigned short* __restrict__ xT, const unsigned short* __restrict__ poO,
        const float* __restrict__ pol,
        const unsigned short* __restrict__ w1b, const unsigned short* __restrict__ w1f,
        const float* __restrict__ b1f, unsigned short* __restrict__ h1,
        float* __restrict__ sums, float* __restrict__ sumsq)
{
    __shared__ unsigned short lA[2][64][40];
    __shared__ unsigned short lB[2][128][40];
    __shared__ float sInv[256];
    const int t = threadIdx.x;
    const int lane = t & 63, wid = t >> 6;
    const int wm = wid >> 1, wn = wid & 1;
    const int lrow = lane & 15, quad = lane >> 4;
    const int o0 = blockIdx.x * 128;
    const int p0 = blockIdx.y * 64;
    const int b = p0 >> 12, n0 = p0 & (SEQ - 1);
    const size_t CH = (size_t)16 * SEQ * HD;

    {
        int h = t >> 6, nn = t & 63;
        int hb = h * BATCH + b;
        float l0 = pol[(size_t)hb * SEQ + n0 + nn];
        float l1 = pol[(size_t)(16 + hb) * SEQ + n0 + nn];
        sInv[t] = 1.0f / (l0 + l1);
    }
    __syncthreads();

    const int arow = t >> 2, acg = (t & 3) * 8;
    const int brow[2] = { (0*256 + t) >> 2, (1*256 + t) >> 2 };

    floatx4 acc[2][4];
#pragma unroll
    for (int i = 0; i < 2; ++i)
#pragma unroll
        for (int j = 0; j < 4; ++j) acc[i][j] = (floatx4){0.f,0.f,0.f,0.f};

    bf16x8 rA, rB[2];
    auto load_tile = [&](int k0) {
        if (k0 < 256) {
            rA = *(const bf16x8*)&xT[(size_t)(p0 + arow) * 256 + k0 + acg];
#pragma unroll
            for (int r = 0; r < 2; ++r)
                rB[r] = *(const bf16x8*)&w1b[(size_t)(o0 + brow[r]) * 512 + k0 + acg];
        } else {
            const int kk2 = k0 - 256;
            const int h = kk2 >> 6, d0 = kk2 & 63, hb = h * BATCH + b;
            const unsigned short* bse = &poO[((size_t)hb * SEQ + n0 + arow) * HD + d0 + acg];
            bf16x8 a0 = *(const bf16x8*)bse;
            bf16x8 a1 = *(const bf16x8*)(bse + CH);
            float inv = sInv[h*64 + arow];
            unsigned short res[8];
#pragma unroll
            for (int i = 0; i < 8; ++i)
                res[i] = f2bf((bf2f((unsigned short)a0[i]) + bf2f((unsigned short)a1[i])) * inv);
            rA = *(const bf16x8*)res;
#pragma unroll
            for (int r = 0; r < 2; ++r)
                rB[r] = *(const bf16x8*)&w1f[(size_t)(o0 + brow[r]) * 256 + kk2 + acg];
        }
    };

    load_tile(0);
    *(bf16x8*)&lA[0][arow][acg] = rA;
#pragma unroll
    for (int r = 0; r < 2; ++r) *(bf16x8*)&lB[0][brow[r]][acg] = rB[r];
    __syncthreads();

    int p = 0;
    for (int kc = 0; kc < 16; ++kc) {
        const bool pre = (kc + 1 < 16);
        if (pre) load_tile((kc + 1) * 32);
        bf16x8 aF[2], bF[4];
        const int kq = quad * 8;
#pragma unroll
        for (int mt = 0; mt < 2; ++mt)
            aF[mt] = *(const bf16x8*)&lA[p][wm*32 + mt*16 + lrow][kq];
#pragma unroll
        for (int nt = 0; nt < 4; ++nt)
            bF[nt] = *(const bf16x8*)&lB[p][wn*64 + nt*16 + lrow][kq];
#pragma unroll
        for (int mt = 0; mt < 2; ++mt)
#pragma unroll
            for (int nt = 0; nt < 4; ++nt)
                acc[mt][nt] = MFMA(aF[mt], bF[nt], acc[mt][nt]);
        if (pre) {
            *(bf16x8*)&lA[p^1][arow][acg] = rA;
#pragma unroll
            for (int r = 0; r < 2; ++r) *(bf16x8*)&lB[p^1][brow[r]][acg] = rB[r];
        }
        __syncthreads();
        p ^= 1;
    }
#pragma unroll
    for (int nt = 0; nt < 4; ++nt) {
        int o = o0 + wn*64 + nt*16 + lrow;
        float bvv = b1f[o];
        float s = 0.f, qs = 0.f;
#pragma unroll
        for (int mt = 0; mt < 2; ++mt)
#pragma unroll
            for (int j = 0; j < 4; ++j) {
                int pos = p0 + wm*32 + mt*16 + quad*4 + j;
                float val = acc[mt][nt][j] + bvv;
                h1[(size_t)pos * 512 + o] = f2bf(val);
                s += val; qs += val * val;
            }
        s  += __shfl_xor(s, 16);  s  += __shfl_xor(s, 32);
        qs += __shfl_xor(qs, 16); qs += __shfl_xor(qs, 32);
        if (lane < 16) {
            atomicAdd(&sums[o], s);
            atomicAdd(&sumsq[o], qs);
        }
    }
}

// ---------------------------------------------------------------------------
// mlp2 (bf16 W, inline bn_final, LDS double-buffered):
// out[b][o][n] f32 = W2 @ relu(bn(h1))^T + bias. grid (2, NPOS/64).
// ---------------------------------------------------------------------------
__global__ __launch_bounds__(256) void gemm_mlp2(
        const unsigned short* __restrict__ W2, const unsigned short* __restrict__ h1,
        const float* __restrict__ bias,
        const float* __restrict__ sums, const float* __restrict__ sumsq,
        const float* __restrict__ gamma, const float* __restrict__ beta,
        float* __restrict__ out)
{
    __shared__ unsigned short lA[2][128][40];
    __shared__ unsigned short lB[2][64][40];
    __shared__ float sSc[512], sSh[512];
    const int t = threadIdx.x;
    const int lane = t & 63, wid = t >> 6;
    const int wm = wid >> 1, wn = wid & 1;
    const int lrow = lane & 15, quad = lane >> 4;
    const int o0 = blockIdx.x * 128;
    const int p0 = blockIdx.y * 64;

#pragma unroll
    for (int cc = 0; cc < 2; ++cc) {
        int c = cc * 256 + t;
        float mean = sums[c] * (1.0f / NPOS);
        float var  = sumsq[c] * (1.0f / NPOS) - mean * mean;
        float sc = gamma[c] * rsqrtf(var + 1e-5f);
        sSc[c] = sc;
        sSh[c] = beta[c] - mean * sc;
    }
    __syncthreads();

    const int arow[2] = { (0*256 + t) >> 2, (1*256 + t) >> 2 };
    const int acg = (t & 3) * 8;
    const int brow = t >> 2;

    floatx4 acc[4][2];
#pragma unroll
    for (int i = 0; i < 4; ++i)
#pragma unroll
        for (int j = 0; j < 2; ++j) acc[i][j] = (floatx4){0.f,0.f,0.f,0.f};

    bf16x8 rW[2], rH;
    auto load_tile = [&](int k0) {
#pragma unroll
        for (int r = 0; r < 2; ++r)
            rW[r] = *(const bf16x8*)&W2[(size_t)(o0 + arow[r]) * 512 + k0 + acg];
        bf16x8 hv = *(const bf16x8*)&h1[(size_t)(p0 + brow) * 512 + k0 + acg];
        unsigned short res[8];
#pragma unroll
        for (int i = 0; i < 8; ++i) {
            int c = k0 + acg + i;
            float f = bf2f((unsigned short)hv[i]);
            f = fmaxf(f * sSc[c] + sSh[c], 0.f);
            res[i] = f2bf(f);
        }
        rH = *(const bf16x8*)res;
    };

    load_tile(0);
#pragma unroll
    for (int r = 0; r < 2; ++r) *(bf16x8*)&lA[0][arow[r]][acg] = rW[r];
    *(bf16x8*)&lB[0][brow][acg] = rH;
    __syncthreads();

    int p = 0;
    for (int kc = 0; kc < 16; ++kc) {
        const bool pre = (kc + 1 < 16);
        if (pre) load_tile((kc + 1) * 32);
        bf16x8 aF[4], bF[2];
        const int kq = quad * 8;
#pragma unroll
        for (int mt = 0; mt < 4; ++mt)
            aF[mt] = *(const bf16x8*)&lA[p][wm*64 + mt*16 + lrow][kq];
#pragma unroll
        for (int nt = 0; nt < 2; ++nt)
            bF[nt] = *(const bf16x8*)&lB[p][wn*32 + nt*16 + lrow][kq];
#pragma unroll
        for (int mt = 0; mt < 4; ++mt)
#pragma unroll
            for (int nt = 0; nt < 2; ++nt)
                acc[mt][nt] = MFMA(aF[mt], bF[nt], acc[mt][nt]);
        if (pre) {
#pragma unroll
            for (int r = 0; r < 2; ++r) *(bf16x8*)&lA[p^1][arow[r]][acg] = rW[r];
            *(bf16x8*)&lB[p^1][brow][acg] = rH;
        }
        __syncthreads();
        p ^= 1;
    }
#pragma unroll
    for (int mt = 0; mt < 4; ++mt)
#pragma unroll
        for (int j = 0; j < 4; ++j) {
            int o = o0 + wm*64 + mt*16 + quad*4 + j;
            float bvv = bias[o];
#pragma unroll
            for (int nt = 0; nt < 2; ++nt) {
                int pos = p0 + wn*32 + nt*16 + lrow;
                int b = pos >> 12, n = pos & (SEQ - 1);
                out[((size_t)b * D_MODEL + o) * SEQ + n] = acc[mt][nt][j] + bvv;
            }
        }
}

// ---------------------------------------------------------------------------
extern "C" void kernel_launch(void* const* d_in, const int* in_sizes, int n_in,
                              void* d_out, int out_size, void* d_ws, size_t ws_size,
                              hipStream_t stream)
{
    (void)in_sizes; (void)n_in; (void)out_size; (void)ws_size;
    const float* x        = (const float*)d_in[0];
    const float* source   = (const float*)d_in[1];
    const float* pq_w     = (const float*)d_in[2];
    const float* pq_b     = (const float*)d_in[3];
    const float* pk_w     = (const float*)d_in[4];
    const float* pk_b     = (const float*)d_in[5];
    const float* pv_w     = (const float*)d_in[6];
    const float* pv_b     = (const float*)d_in[7];
    const float* merge_w  = (const float*)d_in[8];
    const float* merge_b  = (const float*)d_in[9];
    const float* mlp1_w   = (const float*)d_in[10];
    const float* mlp1_b   = (const float*)d_in[11];
    const float* bn_gamma = (const float*)d_in[12];
    const float* bn_beta  = (const float*)d_in[13];
    const float* mlp2_w   = (const float*)d_in[14];
    const float* mlp2_b   = (const float*)d_in[15];
    float* out = (float*)d_out;

    char* ws = (char*)d_ws;
    const size_t MB = 1ull << 20;
    unsigned short* xT   = (unsigned short*)(ws);             //  8 MB [pos][256]
    unsigned short* srcT = (unsigned short*)(ws + 8*MB);      //  8 MB [pos][256]
    unsigned short* q    = (unsigned short*)(ws + 16*MB);     //  8 MB [bh][n][64]
    unsigned short* kk   = (unsigned short*)(ws + 24*MB);     //  8 MB [bh][m][64]
    unsigned short* v    = (unsigned short*)(ws + 32*MB);     //  8 MB [bh][64][m]
    unsigned short* poO  = (unsigned short*)(ws + 40*MB);     // 16 MB bf16 partial O
    unsigned short* h1   = (unsigned short*)(ws + 57*MB);     // 16 MB [pos][512]
    float* pol = (float*)(ws + 73*MB);                        // 512 KB partial l
    unsigned short* wqb = (unsigned short*)(ws + 74*MB);
    unsigned short* wkb = wqb + 65536;
    unsigned short* wvb = wkb + 65536;
    unsigned short* wmt = wvb + 65536;                        // [c'][o] 128 KB
    unsigned short* w1b = wmt + 65536;                        // 512 KB full mlp1_w
    unsigned short* w2b = w1b + 262144;                       // 256 KB
    unsigned short* w1f = w2b + 131072;                       // 256 KB folded
    float* b1f = (float*)(w1f + 131072);                      // 512 folded bias
    float* bn_sum = b1f + 512;
    float* bn_sumsq = bn_sum + 512;

    hipMemsetAsync(bn_sum, 0, 1024 * sizeof(float), stream);

    prep<<<dim3(1152), 256, 0, stream>>>(
        pq_w, pk_w, pv_w, merge_w, mlp1_w, mlp2_w, x, source,
        wqb, wkb, wvb, wmt, w1b, w2b, xT, srcT);
    prep2<<<dim3(2, 9), 256, 0, stream>>>(mlp1_w, mlp1_b, merge_b, wmt, w1f, b1f);
    proj_qkv_all<<<dim3(6, SEQ/128, BATCH), 256, 0, stream>>>(
        wqb, pq_b, wkb, pk_b, wvb, pv_b, xT, srcT, q, kk, v);
    flash_attn<<<dim3(16*MCHUNKS, SEQ/128), 256, 0, stream>>>(q, kk, v, poO, pol);
    gemm_mlp1<<<dim3(4, NPOS/64), 256, 0, stream>>>(
        xT, poO, pol, w1b, w1f, b1f, h1, bn_sum, bn_sumsq);
    gemm_mlp2<<<dim3(2, NPOS/64), 256, 0, stream>>>(
        w2b, h1, mlp2_b, bn_sum, bn_sumsq, bn_gamma, bn_beta, out);
}